// Round 16
// baseline (389.792 us; speedup 1.0000x reference)
//
#include <hip/hip_runtime.h>
#include <hip/hip_bf16.h>

#define TS    2048
#define TT    4096    // B*S
#define TCHUNK 512

typedef __bf16 bf16;
typedef __bf16 bf16x8 __attribute__((ext_vector_type(8)));
typedef __bf16 bf16x4 __attribute__((ext_vector_type(4)));
typedef float  f32x4  __attribute__((ext_vector_type(4)));

#define QPL ((size_t)TT*1024)
#define KPL ((size_t)TT*256)
#define VPL ((size_t)8*64*TS)
#define APL ((size_t)TT*1024)
#define H1PL ((size_t)TT*1024)

__device__ __forceinline__ f32x4 mfma16(bf16x8 a, bf16x8 b, f32x4 c){
  return __builtin_amdgcn_mfma_f32_16x16x32_bf16(a, b, c, 0, 0, 0);
}
__device__ __forceinline__ void gload_lds16(const void* g, void* lds){
  __builtin_amdgcn_global_load_lds(
      (const __attribute__((address_space(1))) unsigned int*)g,
      (__attribute__((address_space(3))) unsigned int*)lds, 16, 0, 0);
}
// 2-limb split; 3 cross products (hh,hm,mh) retain ~2^-18 relative accuracy.
__device__ __forceinline__ void split2f(float x, bf16& h, bf16& m){
  h = (bf16)x; m = (bf16)(x - (float)h);
}

// ---------------- batched 2-way weight transpose: z=0 w_q, 1 w_k, 2 w_v, 3 w_o ----------------
__global__ __launch_bounds__(256) void tcvt2_all_k(const float* __restrict__ wq, const float* __restrict__ wk,
                                                   const float* __restrict__ wv, const float* __restrict__ wo,
                                                   bf16* __restrict__ wqkv2, bf16* __restrict__ wo2){
  int z = blockIdx.z;
  const float* src; bf16* dst; int C; long pl, doff;
  if (z==0){ src=wq; dst=wqkv2; C=1024; pl=(long)1536*1024; doff=0; }
  else if (z==1){ src=wk; dst=wqkv2; C=256; pl=(long)1536*1024; doff=(long)1024*1024; }
  else if (z==2){ src=wv; dst=wqkv2; C=256; pl=(long)1536*1024; doff=(long)1280*1024; }
  else { src=wo; dst=wo2; C=1024; pl=(long)1024*1024; doff=0; }
  int c0 = blockIdx.x*32;
  if (c0 >= C) return;
  __shared__ float tile[32][33];
  int r0 = blockIdx.y*32;
  int tx = threadIdx.x, ty = threadIdx.y;
  #pragma unroll
  for (int i=0;i<4;i++)
    tile[ty+i*8][tx] = src[(size_t)(r0+ty+i*8)*C + c0+tx];
  __syncthreads();
  #pragma unroll
  for (int i=0;i<4;i++){
    float v = tile[tx][ty+i*8];
    bf16 h,m; split2f(v,h,m);
    size_t o = doff + (size_t)(c0+ty+i*8)*1024 + r0+tx;
    dst[o] = h; dst[pl + o] = m;
  }
}

// ---------------- batched MoE weight transpose (1-way bf16), g/u 16-row-interleaved ----------------
__global__ __launch_bounds__(256) void tcvt_moe_k(const float* __restrict__ shwg, const float* __restrict__ shwu,
                                                  const float* __restrict__ shwd, const float* __restrict__ ewg,
                                                  const float* __restrict__ ewu, const float* __restrict__ ewd,
                                                  bf16* __restrict__ shwgu, bf16* __restrict__ shwd_t,
                                                  bf16* __restrict__ ewgu, bf16* __restrict__ ewd_t){
  int z = blockIdx.z;
  const float* src; bf16* dst; int mode;
  if (z==0){ src=shwg; dst=shwgu; mode=0; }
  else if (z==1){ src=shwu; dst=shwgu; mode=1; }
  else if (z==2){ src=shwd; dst=shwd_t; mode=2; }
  else if (z<11){ int e=z-3;  src=ewg+(size_t)e*1048576; dst=ewgu+(size_t)e*2097152; mode=0; }
  else if (z<19){ int e=z-11; src=ewu+(size_t)e*1048576; dst=ewgu+(size_t)e*2097152; mode=1; }
  else          { int e=z-19; src=ewd+(size_t)e*1048576; dst=ewd_t+(size_t)e*1048576; mode=2; }
  __shared__ float tile[32][33];
  int r0 = blockIdx.y*32, c0 = blockIdx.x*32;
  int tx = threadIdx.x, ty = threadIdx.y;
  #pragma unroll
  for (int i=0;i<4;i++)
    tile[ty+i*8][tx] = src[(size_t)(r0+ty+i*8)*1024 + c0+tx];
  __syncthreads();
  #pragma unroll
  for (int i=0;i<4;i++){
    int c = c0+ty+i*8;
    int orow = (mode==2) ? c : ((c>>4)*32 + (c&15) + (mode==1?16:0));
    dst[(size_t)orow*1024 + r0+tx] = (bf16)tile[tx][ty+i*8];
  }
}

// ---------------- RMSNorm f32 -> 2-way split bf16 planes ----------------
__global__ __launch_bounds__(256) void rmsnorm2_k(const float* __restrict__ x, const float* __restrict__ g,
                                                  bf16* __restrict__ o2){
  int row = blockIdx.x, tid = threadIdx.x, wid = tid>>6, lane = tid&63;
  f32x4 v = ((const f32x4*)(x + (size_t)row*1024))[tid];
  float ss = v[0]*v[0]+v[1]*v[1]+v[2]*v[2]+v[3]*v[3];
  #pragma unroll
  for (int m=1;m<64;m<<=1) ss += __shfl_xor(ss, m);
  __shared__ float red[4];
  if (lane==0) red[wid] = ss;
  __syncthreads();
  float tot = red[0]+red[1]+red[2]+red[3];
  float inv = rsqrtf(tot*(1.f/1024.f) + 1e-6f);
  f32x4 gv = ((const f32x4*)g)[tid];
  #pragma unroll
  for (int i=0;i<4;i++){
    float val = v[i]*inv*gv[i];
    bf16 h,m; split2f(val,h,m);
    size_t idx = (size_t)row*1024 + tid*4 + i;
    o2[idx] = h; o2[H1PL + idx] = m;
  }
}

// ---------------- plain bf16 GEMM (MoE path), BK=64, XOR-swizzled, 128x128, 2-phase dbuf ----------------
// OUT: 1 = bf16, 2 = fused silu (g/u 16-interleaved B, ldc = N/2)
// T3 minimal pipeline: STAGE(next) issued BEFORE compute(cur); one vmcnt(0)+barrier per tile.
// LDS 64KB -> 2 blocks/CU (equals measured effective occupancy; no cliff).
template<int OUT, int GATHER, int GROUPED>
__global__ __launch_bounds__(256) void gemm_k(
    const bf16* __restrict__ Aptr, int lda,
    const bf16* __restrict__ Bt, long bMatStride,
    void* __restrict__ Cout, int ldc,
    const float* __restrict__ resid,
    const int* __restrict__ gidx,
    const int* __restrict__ grpBase,
    const int* __restrict__ grpCnt,
    int M, int K){
  int tid = threadIdx.x;
  int wid = tid >> 6, lane = tid & 63;
  int lr = lane & 15, lg = lane >> 4;
  int e = blockIdx.z;
  int base = GROUPED ? grpBase[e] : 0;
  int cnt  = GROUPED ? grpCnt[e]  : M;
  int m0, bn0;
  if (GROUPED){
    m0 = blockIdx.y * 128;
    bn0 = blockIdx.x * 128;
  } else {
    int gx = gridDim.x;
    int bid = blockIdx.y*gx + blockIdx.x;
    int cpx = (gx*gridDim.y)>>3;
    int swz = (bid&7)*cpx + (bid>>3);
    m0 = (swz/gx) * 128;
    bn0 = (swz%gx) * 128;
  }
  if (m0 >= cnt) return;
  const bf16* Bte = Bt + (size_t)e * bMatStride;

  __shared__ __align__(16) bf16 As[2][128*64];
  __shared__ __align__(16) bf16 Bs[2][128*64];

  int lrow = lane >> 3;                 // 0..7
  int cb   = (lane & 7) ^ lrow;         // pre-swizzled global col-block (16B units)
  int arow[4], brow[4];
  #pragma unroll
  for (int i=0;i<4;i++){
    int r = wid*8 + i*32 + lrow;
    int ar = m0 + r; if (ar > cnt-1) ar = cnt-1;
    arow[i] = GATHER ? gidx[base + ar] : (base + ar);
    brow[i] = bn0 + r;
  }

  f32x4 zero4 = {0.f,0.f,0.f,0.f};
  f32x4 acc[4][4];
  #pragma unroll
  for (int m=0;m<4;m++)
    #pragma unroll
    for (int n=0;n<4;n++) acc[m][n] = zero4;

  int wr = (wid>>1)*64, wc = (wid&1)*64;
  int sw = lr & 7;   // read-side XOR (row&7 == lr&7 since wr,m*16 are multiples of 8)

  auto STAGE = [&](int buf, int k0){
    #pragma unroll
    for (int i=0;i<4;i++){
      gload_lds16(Aptr + (size_t)arow[i]*lda + k0 + cb*8, (char*)As[buf] + wid*1024 + i*4096);
      gload_lds16(Bte  + (size_t)brow[i]*K   + k0 + cb*8, (char*)Bs[buf] + wid*1024 + i*4096);
    }
  };

  STAGE(0, 0);
  asm volatile("s_waitcnt vmcnt(0)" ::: "memory");
  __syncthreads();

  int nt = K >> 6;
  for (int t=0; t<nt; t++){
    int cur = t & 1;
    if (t+1 < nt) STAGE(cur^1, (t+1)<<6);     // next-tile loads in flight during MFMA
    #pragma unroll
    for (int ks=0; ks<2; ks++){
      int pos = (ks*4 + lg) ^ sw;
      bf16x8 af[4], bfr[4];
      #pragma unroll
      for (int m=0;m<4;m++)
        af[m] = *(const bf16x8*)&As[cur][(wr + m*16 + lr)*64 + pos*8];
      #pragma unroll
      for (int n=0;n<4;n++)
        bfr[n] = *(const bf16x8*)&Bs[cur][(wc + n*16 + lr)*64 + pos*8];
      #pragma unroll
      for (int m=0;m<4;m++)
        #pragma unroll
        for (int n=0;n<4;n++)
          acc[m][n] = mfma16(af[m], bfr[n], acc[m][n]);
    }
    asm volatile("s_waitcnt vmcnt(0)" ::: "memory");
    __syncthreads();
  }
  #pragma unroll
  for (int m=0;m<4;m++){
    #pragma unroll
    for (int j=0;j<4;j++){
      int gr = m0 + wr + m*16 + lg*4 + j;
      if (gr < cnt){
        size_t orow = (size_t)(base + gr);
        if (OUT==2){
          #pragma unroll
          for (int np=0;np<2;np++){
            float gv = acc[m][2*np][j], uv = acc[m][2*np+1][j];
            float ov = gv * uv / (1.f + __expf(-gv));
            int f = ((bn0+wc)>>1) + np*16 + lr;
            ((bf16*)Cout)[orow*ldc + f] = (bf16)ov;
          }
        } else {
          #pragma unroll
          for (int n=0;n<4;n++){
            int gc = bn0 + wc + n*16 + lr;
            ((bf16*)Cout)[orow*ldc + gc] = (bf16)acc[m][n][j];
          }
        }
      }
    }
  }
}

// ---------------- split-2 precise GEMM: 3 products (hh,hm,mh), C f32 (+resid) ----------------
template<int RESID>
__global__ __launch_bounds__(256) void gemm2_k(
    const bf16* __restrict__ A2, long aPL, int lda,
    const bf16* __restrict__ B2, long bPL, int K,
    float* __restrict__ C, int ldc,
    const float* __restrict__ resid){
  int tid = threadIdx.x;
  int wid = tid >> 6, lane = tid & 63;
  int lr = lane & 15, lg = lane >> 4;
  int gx = gridDim.x;
  int bid = blockIdx.y*gx + blockIdx.x;
  int cpx = (gx*gridDim.y)>>3;
  int swz = (bid&7)*cpx + (bid>>3);
  int m0 = (swz/gx) * 128;
  int bn0 = (swz%gx) * 128;

  __shared__ __align__(16) bf16 As[2*128*32];
  __shared__ __align__(16) bf16 Bs[2*128*32];

  int rA0 = tid >> 2, colA = (tid & 3) * 8;
  f32x4 zero4 = {0.f,0.f,0.f,0.f};
  f32x4 acc[4][4];
  #pragma unroll
  for (int m=0;m<4;m++)
    #pragma unroll
    for (int n=0;n<4;n++) acc[m][n] = zero4;

  int wr = (wid>>1)*64, wc = (wid&1)*64;

  for (int k0 = 0; k0 < K; k0 += 32){
    #pragma unroll
    for (int p=0;p<2;p++){
      #pragma unroll
      for (int i=0;i<2;i++){
        int r = rA0 + i*64;
        gload_lds16(A2 + (size_t)p*aPL + (size_t)(m0 + r)*lda + k0 + colA,
                    (char*)As + p*8192 + wid*1024 + i*4096);
        gload_lds16(B2 + (size_t)p*bPL + (size_t)(bn0 + r)*K + k0 + colA,
                    (char*)Bs + p*8192 + wid*1024 + i*4096);
      }
    }
    asm volatile("s_waitcnt vmcnt(0)" ::: "memory");
    __syncthreads();
    bf16x8 af[2][4], bfr[2][4];
    #pragma unroll
    for (int p=0;p<2;p++){
      #pragma unroll
      for (int m=0;m<4;m++) af[p][m]  = *(const bf16x8*)&As[p*4096 + (wr + m*16 + lr)*32 + lg*8];
      #pragma unroll
      for (int n=0;n<4;n++) bfr[p][n] = *(const bf16x8*)&Bs[p*4096 + (wc + n*16 + lr)*32 + lg*8];
    }
    #pragma unroll
    for (int m=0;m<4;m++)
      #pragma unroll
      for (int n=0;n<4;n++){
        f32x4 a = acc[m][n];
        a = mfma16(af[0][m], bfr[0][n], a);   // hh
        a = mfma16(af[0][m], bfr[1][n], a);   // hm
        a = mfma16(af[1][m], bfr[0][n], a);   // mh
        acc[m][n] = a;
      }
    __syncthreads();
  }
  #pragma unroll
  for (int m=0;m<4;m++){
    #pragma unroll
    for (int j=0;j<4;j++){
      size_t orow = (size_t)(m0 + wr + m*16 + lg*4 + j);
      #pragma unroll
      for (int n=0;n<4;n++){
        int gc = bn0 + wc + n*16 + lr;
        float v = acc[m][n][j];
        if (RESID) v += resid[orow*ldc + gc];
        C[orow*ldc + gc] = v;
      }
    }
  }
}

// ---------------- merged: per-head QK RMSNorm+RoPE (blocks < 20480) and V transpose (rest) ----------------
__global__ __launch_bounds__(256) void rv2_k(const float* __restrict__ qkv, bf16* __restrict__ Q2,
                                             bf16* __restrict__ K2, bf16* __restrict__ V2,
                                             const int* __restrict__ idxp,
                                             const float* __restrict__ qg, const float* __restrict__ kg){
  int bid = blockIdx.x;
  if (bid < 20480){
    int tid = threadIdx.x, wid = tid>>6, lane = tid&63;
    int u = bid*4 + wid;   // 0 .. TT*20-1
    int t = u / 20, r = u % 20;
    bool isq = (r < 16);
    int srcOff = isq ? r*64 : 1024 + (r-16)*64;
    float val = qkv[(size_t)t*1536 + srcOff + lane];
    float ss = val*val;
    #pragma unroll
    for (int m=1;m<64;m<<=1) ss += __shfl_xor(ss, m);
    float inv = rsqrtf(ss*(1.f/64.f) + 1e-6f);
    const float* gm = isq ? qg : kg;
    val = val * inv * gm[lane];
    bool rope = ((idxp[0] + 1) % 4) != 0;
    if (rope){
      int s = t & (TS-1);
      float fi = (float)(lane & ~1);
      float theta = (float)exp((double)fi * -0.14391156831212787);
      float ang = (float)s * theta;
      float sn, cs;
      sincosf(ang, &sn, &cs);
      float other = __shfl_xor(val, 1);
      val = (lane & 1) ? (other*sn + val*cs) : (val*cs - other*sn);
    }
    bf16 h,m2; split2f(val,h,m2);
    if (isq){
      size_t base = (size_t)t*1024 + r*64 + lane;
      Q2[base] = h; Q2[QPL + base] = m2;
    } else {
      size_t base = (size_t)t*256 + (r-16)*64 + lane;
      K2[base] = h; K2[KPL + base] = m2;
    }
  } else {
    int vb = bid - 20480;              // 0..1023
    int xb = vb & 1, yb = (vb>>1) & 63, z = vb >> 7;   // z = b*4+kvh
    __shared__ float tile[32][33];
    const float* s = qkv + (size_t)(z>>2)*((size_t)TS*1536) + (z&3)*64 + 1280;
    int r0 = yb*32, c0 = xb*32;
    int tx = threadIdx.x & 31, ty = threadIdx.x >> 5;
    #pragma unroll
    for (int i=0;i<4;i++)
      tile[ty+i*8][tx] = s[(size_t)(r0+ty+i*8)*1536 + c0+tx];
    __syncthreads();
    size_t zb = (size_t)z*(64*TS);
    #pragma unroll
    for (int i=0;i<4;i++){
      float v = tile[tx][ty+i*8];
      bf16 h,m; split2f(v,h,m);
      size_t o = zb + (size_t)(c0+ty+i*8)*TS + r0+tx;
      V2[o] = h; V2[VPL + o] = m;
    }
  }
}

// ---------------- precise chunked-causal GQA flash attention (2-limb, 3-product) ----------------
__global__ __launch_bounds__(256) void attn2_k(const bf16* __restrict__ Q2, const bf16* __restrict__ K2,
                                               const bf16* __restrict__ V2, bf16* __restrict__ A2,
                                               const int* __restrict__ idxp){
  int tid = threadIdx.x, wid = tid>>6, lane = tid&63;
  int lr = lane&15, lg = lane>>4;
  int flat = (blockIdx.z*gridDim.y + blockIdx.y)*gridDim.x + blockIdx.x;
  int swz = (flat&7)*128 + (flat>>3);
  int qt = swz & 31, h = (swz>>5)&15, b = swz>>9;
  int kvh = h >> 2;
  int q0 = qt*64;
  bool rope = ((idxp[0]+1) % 4) != 0;
  int kstart = rope ? (q0 / TCHUNK) * TCHUNK : 0;
  int ntiles = (q0 + 64 - kstart) >> 5;

  __shared__ __align__(16) bf16 Ks[2*32*64];   // swizzled
  __shared__ __align__(16) bf16 Vs[2*64*32];   // linear
  __shared__ __align__(16) bf16 Ps[4][2][16*32];

  bf16x8 qf[2][2];
  {
    size_t qrow = (size_t)(b*TS + q0 + wid*16 + lr);
    #pragma unroll
    for (int p=0;p<2;p++)
      #pragma unroll
      for (int kf=0;kf<2;kf++)
        qf[p][kf] = *(const bf16x8*)&Q2[(size_t)p*QPL + qrow*1024 + h*64 + kf*32 + lg*8];
  }

  int krow = tid>>3;
  int kcb  = (tid&7) ^ (krow&7);
  int vrow = tid>>2;
  int vcb  = tid&3;

  f32x4 o[4];
  f32x4 zero4 = {0.f,0.f,0.f,0.f};
  #pragma unroll
  for (int n=0;n<4;n++) o[n] = zero4;
  float mrow[4], lrow[4];
  #pragma unroll
  for (int j=0;j<4;j++){ mrow[j] = -1e30f; lrow[j] = 0.f; }

  for (int kt=0; kt<ntiles; kt++){
    int kt0 = kstart + kt*32;
    #pragma unroll
    for (int p=0;p<2;p++){
      gload_lds16(K2 + (size_t)p*KPL + ((size_t)(b*TS + kt0 + krow))*256 + kvh*64 + kcb*8,
                  (char*)Ks + p*4096 + wid*1024);
      gload_lds16(V2 + (size_t)p*VPL + ((size_t)((b*4 + kvh)*64 + vrow))*TS + kt0 + vcb*8,
                  (char*)Vs + p*4096 + wid*1024);
    }
    asm volatile("s_waitcnt vmcnt(0)" ::: "memory");
    __syncthreads();

    // QK^T: 3 limb-products (x2 k-frags = 6 MFMA per cf)
    f32x4 sc[2];
    #pragma unroll
    for (int cf=0; cf<2; cf++){
      int r = cf*16 + lr;
      int sw = (lr&7) << 3;
      bf16x8 kh0 = *(const bf16x8*)&Ks[0*2048 + r*64 + (((lg  )<<3) ^ sw)];
      bf16x8 kh1 = *(const bf16x8*)&Ks[0*2048 + r*64 + (((lg+4)<<3) ^ sw)];
      bf16x8 km0 = *(const bf16x8*)&Ks[1*2048 + r*64 + (((lg  )<<3) ^ sw)];
      bf16x8 km1 = *(const bf16x8*)&Ks[1*2048 + r*64 + (((lg+4)<<3) ^ sw)];
      f32x4 a = zero4;
      a = mfma16(qf[0][0], kh0, a); a = mfma16(qf[0][1], kh1, a);  // hh
      a = mfma16(qf[0][0], km0, a); a = mfma16(qf[0][1], km1, a);  // hm
      a = mfma16(qf[1][0], kh0, a); a = mfma16(qf[1][1], kh1, a);  // mh
      sc[cf] = a;
    }
    #pragma unroll
    for (int j=0;j<4;j++){
      int qtok = q0 + wid*16 + lg*4 + j;
      float pmax = -1e30f;
      #pragma unroll
      for (int cf=0;cf<2;cf++){
        int ktok = kt0 + cf*16 + lr;
        float sv = (ktok <= qtok) ? sc[cf][j]*0.125f : -1e30f;
        sc[cf][j] = sv;
        pmax = fmaxf(pmax, sv);
      }
      #pragma unroll
      for (int m=1;m<16;m<<=1) pmax = fmaxf(pmax, __shfl_xor(pmax, m));
      float mnew = fmaxf(mrow[j], pmax);
      float corr = __expf(mrow[j]-mnew);
      float psum = 0.f;
      #pragma unroll
      for (int cf=0;cf<2;cf++){
        float p = __expf(sc[cf][j]-mnew);
        sc[cf][j] = p;
        psum += p;
      }
      #pragma unroll
      for (int m=1;m<16;m<<=1) psum += __shfl_xor(psum, m);
      lrow[j] = lrow[j]*corr + psum;
      mrow[j] = mnew;
      #pragma unroll
      for (int n=0;n<4;n++) o[n][j] *= corr;
      #pragma unroll
      for (int cf=0;cf<2;cf++){
        float p = sc[cf][j];
        bf16 ph = (bf16)p;
        bf16 pl = (bf16)(p - (float)ph);
        int pidx = (lg*4+j)*32 + cf*16 + lr;
        Ps[wid][0][pidx] = ph;
        Ps[wid][1][pidx] = pl;
      }
    }
    __syncthreads();
    // PV: 3 limb-products (hh, hm, lh)
    bf16x8 pa0 = *(const bf16x8*)&Ps[wid][0][lr*32 + lg*8];
    bf16x8 pa1 = *(const bf16x8*)&Ps[wid][1][lr*32 + lg*8];
    #pragma unroll
    for (int n=0;n<4;n++){
      bf16x8 vh = *(const bf16x8*)&Vs[0*2048 + (n*16+lr)*32 + lg*8];
      bf16x8 vm = *(const bf16x8*)&Vs[1*2048 + (n*16+lr)*32 + lg*8];
      f32x4 a = o[n];
      a = mfma16(pa0, vh, a);   // hh
      a = mfma16(pa0, vm, a);   // hm
      a = mfma16(pa1, vh, a);   // lh
      o[n] = a;
    }
    __syncthreads();
  }
  #pragma unroll
  for (int j=0;j<4;j++){
    int qtok = q0 + wid*16 + lg*4 + j;
    float invl = 1.f / lrow[j];
    size_t rowb = ((size_t)(b*TS + qtok))*1024 + h*64;
    #pragma unroll
    for (int n=0;n<4;n++){
      float v = o[n][j]*invl;
      bf16 h2,m2; split2f(v,h2,m2);
      size_t oidx = rowb + n*16 + lr;
      A2[oidx] = h2; A2[APL + oidx] = m2;
    }
  }
}

// ---------------- fused f32 rmsnorm(h2) + router ----------------
__global__ __launch_bounds__(256) void rmsrouter_k(const float* __restrict__ x2, const float* __restrict__ g2,
                                                   const float* __restrict__ wr, bf16* __restrict__ h2,
                                                   int* __restrict__ topi, float* __restrict__ topw){
  int tid = threadIdx.x, wid = tid>>6, lane = tid&63;
  int t = blockIdx.x*4 + wid;
  const float* row = x2 + (size_t)t*1024;
  f32x4 xv[4];
  float ss = 0.f;
  #pragma unroll
  for (int j=0;j<4;j++){
    xv[j] = ((const f32x4*)row)[lane + j*64];
    ss += xv[j][0]*xv[j][0]+xv[j][1]*xv[j][1]+xv[j][2]*xv[j][2]+xv[j][3]*xv[j][3];
  }
  #pragma unroll
  for (int m=1;m<64;m<<=1) ss += __shfl_xor(ss, m);
  float inv = 1.f / sqrtf(ss*(1.f/1024.f) + 1e-6f);
  float a[8] = {0,0,0,0,0,0,0,0};
  #pragma unroll
  for (int j=0;j<4;j++){
    bf16x4 hb;
    #pragma unroll
    for (int c=0;c<4;c++){
      int d = (lane + j*64)*4 + c;
      float hv = xv[j][c]*inv*g2[d];
      hb[c] = (bf16)hv;
      f32x4 wa = ((const f32x4*)(wr + (size_t)d*8))[0];
      f32x4 wb = ((const f32x4*)(wr + (size_t)d*8))[1];
      a[0]+=hv*wa[0]; a[1]+=hv*wa[1]; a[2]+=hv*wa[2]; a[3]+=hv*wa[3];
      a[4]+=hv*wb[0]; a[5]+=hv*wb[1]; a[6]+=hv*wb[2]; a[7]+=hv*wb[3];
    }
    *(bf16x4*)(h2 + (size_t)t*1024 + (lane + j*64)*4) = hb;
  }
  #pragma unroll
  for (int e2=0;e2<8;e2++)
    #pragma unroll
    for (int m=1;m<64;m<<=1) a[e2] += __shfl_xor(a[e2], m);
  if (lane==0){
    int i0=0; float l0=a[0];
    #pragma unroll
    for (int e2=1;e2<8;e2++) if (a[e2] > l0){ l0=a[e2]; i0=e2; }
    int i1=-1; float l1=-1e30f;
    #pragma unroll
    for (int e2=0;e2<8;e2++){ if (e2==i0) continue; if (a[e2] > l1){ l1=a[e2]; i1=e2; } }
    float w0 = 1.f/(1.f + __expf(l1 - l0));
    topi[t*2]=i0; topi[t*2+1]=i1;
    topw[t*2]=w0; topw[t*2+1]=1.f-w0;
  }
}

// ---------------- single-block routing build (+ shared-expert group 8) ----------------
__global__ __launch_bounds__(1024) void route_build_k(const int* __restrict__ topi, int* __restrict__ rowsb,
                                                      int* __restrict__ t2p, int* __restrict__ cntp,
                                                      int* __restrict__ basep){
  __shared__ int wcnt[16][8], wbase[16][8], wcur[16][8];
  int tid = threadIdx.x, w = tid>>6;
  if (tid < 128){ wcnt[tid>>3][tid&7]=0; wcur[tid>>3][tid&7]=0; }
  __syncthreads();
  for (int i=tid; i<TT*2; i+=1024) atomicAdd(&wcnt[w][topi[i]], 1);
  __syncthreads();
  if (tid==0){
    int run=0;
    for (int e=0;e<8;e++){
      basep[e]=run; int s=run;
      for (int ww=0;ww<16;ww++){ wbase[ww][e]=run; run+=wcnt[ww][e]; }
      cntp[e]=run-s;
    }
    basep[8]=TT*2; cntp[8]=TT;   // shared expert: identity group
  }
  __syncthreads();
  for (int i=tid; i<TT*2; i+=1024){
    int e = topi[i];
    int p = wbase[w][e] + atomicAdd(&wcur[w][e], 1);
    rowsb[p] = i>>1;
    t2p[i] = p;
  }
  for (int i=tid; i<TT; i+=1024) rowsb[TT*2+i] = i;
}

// ---------------- final combine: out = x2 + sh + w0*e0 + w1*e1 ----------------
__global__ void combine_k(const float* __restrict__ x2, const bf16* __restrict__ eo,
                          const float* __restrict__ topw, const int* __restrict__ t2p,
                          float* __restrict__ out){
  int i = blockIdx.x*256 + threadIdx.x;
  int t = i >> 8, c = (i & 255)*4;
  int p0 = t2p[t*2], p1 = t2p[t*2+1];
  float w0 = topw[t*2], w1 = topw[t*2+1];
  f32x4 a = *(const f32x4*)&x2[(size_t)t*1024 + c];
  bf16x4 e0 = *(const bf16x4*)&eo[(size_t)p0*1024 + c];
  bf16x4 e1 = *(const bf16x4*)&eo[(size_t)p1*1024 + c];
  bf16x4 es = *(const bf16x4*)&eo[((size_t)(TT*2) + t)*1024 + c];
  f32x4 r;
  #pragma unroll
  for (int k=0;k<4;k++) r[k] = a[k] + (float)es[k] + w0*(float)e0[k] + w1*(float)e1[k];
  *(f32x4*)&out[(size_t)t*1024 + c] = r;
}

extern "C" void kernel_launch(void* const* d_in, const int* in_sizes, int n_in,
                              void* d_out, int out_size, void* d_ws, size_t ws_size,
                              hipStream_t stream){
  const float* x        = (const float*)d_in[0];
  const int*   idx      = (const int*)d_in[1];
  const float* gamma1   = (const float*)d_in[2];
  const float* gamma2   = (const float*)d_in[3];
  const float* qg       = (const float*)d_in[4];
  const float* kg       = (const float*)d_in[5];
  const float* w_q      = (const float*)d_in[6];
  const float* w_k      = (const float*)d_in[7];
  const float* w_v      = (const float*)d_in[8];
  const float* w_o      = (const float*)d_in[9];
  const float* w_router = (const float*)d_in[10];
  const float* sh_wg    = (const float*)d_in[11];
  const float* sh_wu    = (const float*)d_in[12];
  const float* sh_wd    = (const float*)d_in[13];
  const float* e_wg     = (const float*)d_in[14];
  const float* e_wu     = (const float*)d_in[15];
  const float* e_wd     = (const float*)d_in[16];
  float* out = (float*)d_out;

  char* ws = (char*)d_ws;
  size_t off = 0;
  auto alloc = [&](size_t n)->char*{ char* p = ws + off; off += (n + 255) & ~(size_t)255; return p; };

  const long PLQKV = (long)1536*1024;
  const long PLSQ  = (long)1024*1024;

  bf16* wqkv2  = (bf16*)alloc((size_t)2*1536*1024*2);
  bf16* wo2    = (bf16*)alloc((size_t)2*1024*1024*2);
  bf16* ewgu_t = (bf16*)alloc((size_t)9*2048*1024*2);   // 9th slot = shared expert
  bf16* ewd_t  = (bf16*)alloc((size_t)9*1024*1024*2);   // 9th slot = shared expert
  bf16* h1s    = (bf16*)alloc((size_t)2*TT*1024*2);
  float* qkvraw= (float*)alloc((size_t)TT*1536*4);
  bf16* q2     = (bf16*)alloc((size_t)2*TT*1024*2);
  bf16* k2     = (bf16*)alloc((size_t)2*TT*256*2);
  bf16* v2     = (bf16*)alloc((size_t)2*8*64*TS*2);
  float* x2    = (float*)alloc((size_t)TT*1024*4);
  bf16* gu     = (bf16*)alloc((size_t)(TT*3)*1024*2);   // 12288 rows
  bf16* eo     = (bf16*)alloc((size_t)(TT*3)*1024*2);   // 12288 rows
  int*   topi  = (int*)alloc((size_t)TT*2*4);
  float* topw  = (float*)alloc((size_t)TT*2*4);
  int*   rowsb = (int*)alloc((size_t)TT*3*4);
  int*   t2p   = (int*)alloc((size_t)TT*2*4);
  int*   cntp  = (int*)alloc(256);
  int*   basep = (int*)alloc(256);
  (void)ws_size; (void)in_sizes; (void)n_in; (void)out_size;

  bf16* shwgu_t = ewgu_t + (size_t)8*2048*1024;  // alias: 9th up slot
  bf16* shwd_t  = ewd_t  + (size_t)8*1024*1024;  // alias: 9th down slot
  bf16* a2      = (bf16*)qkvraw;     // attn output splits (qkvraw dead by then)
  bf16* h2      = q2;                // q2 dead after attention

  dim3 tb(32,8);
  tcvt2_all_k<<<dim3(32,32,4), tb, 0, stream>>>(w_q, w_k, w_v, w_o, wqkv2, wo2);
  tcvt_moe_k<<<dim3(32,32,27), tb, 0, stream>>>(sh_wg, sh_wu, sh_wd, e_wg, e_wu, e_wd,
                                                shwgu_t, shwd_t, ewgu_t, ewd_t);

  rmsnorm2_k<<<TT, 256, 0, stream>>>(x, gamma1, h1s);
  gemm2_k<0><<<dim3(12,32,1), 256, 0, stream>>>(h1s, (long)H1PL, 1024, wqkv2, PLQKV, 1024,
                                                qkvraw, 1536, nullptr);
  rv2_k<<<20480+1024, 256, 0, stream>>>(qkvraw, q2, k2, v2, idx, qg, kg);
  attn2_k<<<dim3(32,16,2), 256, 0, stream>>>(q2, k2, v2, a2, idx);
  gemm2_k<1><<<dim3(8,32,1), 256, 0, stream>>>(a2, (long)APL, 1024, wo2, PLSQ, 1024,
                                               x2, 1024, x);
  rmsrouter_k<<<TT/4, 256, 0, stream>>>(x2, gamma2, w_router, h2, topi, topw);
  route_build_k<<<1, 1024, 0, stream>>>(topi, rowsb, t2p, cntp, basep);
  // unified MoE (8 routed + shared as group 8): up+silu, then down  (BK=64 swizzled, dbuf)
  gemm_k<2,1,1><<<dim3(16,64,9), 256, 0, stream>>>(h2,1024, ewgu_t,(long)2048*1024, gu,1024,
                                                   nullptr, rowsb, basep, cntp, TT, 1024);
  gemm_k<1,0,1><<<dim3(8,64,9), 256, 0, stream>>>(gu,1024, ewd_t,(long)1024*1024, eo,1024,
                                                  nullptr, nullptr, basep, cntp, TT, 1024);
  combine_k<<<TT, 256, 0, stream>>>(x2, eo, topw, t2p, out);
}

// Round 17
// 385.041 us; speedup vs baseline: 1.0123x; 1.0123x over previous
//
#include <hip/hip_runtime.h>
#include <hip/hip_bf16.h>

#define TS    2048
#define TT    4096    // B*S
#define TCHUNK 512

typedef __bf16 bf16;
typedef __bf16 bf16x8 __attribute__((ext_vector_type(8)));
typedef __bf16 bf16x4 __attribute__((ext_vector_type(4)));
typedef float  f32x4  __attribute__((ext_vector_type(4)));

#define QPL ((size_t)TT*1024)
#define KPL ((size_t)TT*256)
#define VPL ((size_t)8*64*TS)
#define APL ((size_t)TT*1024)
#define H1PL ((size_t)TT*1024)

__device__ __forceinline__ f32x4 mfma16(bf16x8 a, bf16x8 b, f32x4 c){
  return __builtin_amdgcn_mfma_f32_16x16x32_bf16(a, b, c, 0, 0, 0);
}
__device__ __forceinline__ void gload_lds16(const void* g, void* lds){
  __builtin_amdgcn_global_load_lds(
      (const __attribute__((address_space(1))) unsigned int*)g,
      (__attribute__((address_space(3))) unsigned int*)lds, 16, 0, 0);
}
// 2-limb split; 3 cross products (hh,hm,mh) retain ~2^-18 relative accuracy.
__device__ __forceinline__ void split2f(float x, bf16& h, bf16& m){
  h = (bf16)x; m = (bf16)(x - (float)h);
}

// ---------------- merged weight conversion ----------------
// z=0..3: 2-limb split transpose (w_q, w_k, w_v, w_o)
// z=4..30: MoE 1-way bf16 transpose (g/u 16-row-interleaved): 4 sh_wg, 5 sh_wu, 6 sh_wd,
//          7..14 e_wg, 15..22 e_wu, 23..30 e_wd
__global__ __launch_bounds__(256) void tcvt_all_k(const float* __restrict__ wq, const float* __restrict__ wk,
                                                  const float* __restrict__ wv, const float* __restrict__ wo,
                                                  const float* __restrict__ shwg, const float* __restrict__ shwu,
                                                  const float* __restrict__ shwd, const float* __restrict__ ewg,
                                                  const float* __restrict__ ewu, const float* __restrict__ ewd,
                                                  bf16* __restrict__ wqkv2, bf16* __restrict__ wo2,
                                                  bf16* __restrict__ shwgu, bf16* __restrict__ shwd_t,
                                                  bf16* __restrict__ ewgu, bf16* __restrict__ ewd_t){
  int z = blockIdx.z;
  __shared__ float tile[32][33];
  int tx = threadIdx.x, ty = threadIdx.y;
  if (z < 4){
    const float* src; bf16* dst; int C; long pl, doff;
    if (z==0){ src=wq; dst=wqkv2; C=1024; pl=(long)1536*1024; doff=0; }
    else if (z==1){ src=wk; dst=wqkv2; C=256; pl=(long)1536*1024; doff=(long)1024*1024; }
    else if (z==2){ src=wv; dst=wqkv2; C=256; pl=(long)1536*1024; doff=(long)1280*1024; }
    else { src=wo; dst=wo2; C=1024; pl=(long)1024*1024; doff=0; }
    int c0 = blockIdx.x*32;
    if (c0 >= C) return;
    int r0 = blockIdx.y*32;
    #pragma unroll
    for (int i=0;i<4;i++)
      tile[ty+i*8][tx] = src[(size_t)(r0+ty+i*8)*C + c0+tx];
    __syncthreads();
    #pragma unroll
    for (int i=0;i<4;i++){
      float v = tile[tx][ty+i*8];
      bf16 h,m; split2f(v,h,m);
      size_t o = doff + (size_t)(c0+ty+i*8)*1024 + r0+tx;
      dst[o] = h; dst[pl + o] = m;
    }
  } else {
    int zz = z - 4;
    const float* src; bf16* dst; int mode;
    if (zz==0){ src=shwg; dst=shwgu; mode=0; }
    else if (zz==1){ src=shwu; dst=shwgu; mode=1; }
    else if (zz==2){ src=shwd; dst=shwd_t; mode=2; }
    else if (zz<11){ int e=zz-3;  src=ewg+(size_t)e*1048576; dst=ewgu+(size_t)e*2097152; mode=0; }
    else if (zz<19){ int e=zz-11; src=ewu+(size_t)e*1048576; dst=ewgu+(size_t)e*2097152; mode=1; }
    else           { int e=zz-19; src=ewd+(size_t)e*1048576; dst=ewd_t+(size_t)e*1048576; mode=2; }
    int r0 = blockIdx.y*32, c0 = blockIdx.x*32;
    #pragma unroll
    for (int i=0;i<4;i++)
      tile[ty+i*8][tx] = src[(size_t)(r0+ty+i*8)*1024 + c0+tx];
    __syncthreads();
    #pragma unroll
    for (int i=0;i<4;i++){
      int c = c0+ty+i*8;
      int orow = (mode==2) ? c : ((c>>4)*32 + (c&15) + (mode==1?16:0));
      dst[(size_t)orow*1024 + r0+tx] = (bf16)tile[tx][ty+i*8];
    }
  }
}

// ---------------- RMSNorm f32 -> 2-way split bf16 planes ----------------
__global__ __launch_bounds__(256) void rmsnorm2_k(const float* __restrict__ x, const float* __restrict__ g,
                                                  bf16* __restrict__ o2){
  int row = blockIdx.x, tid = threadIdx.x, wid = tid>>6, lane = tid&63;
  f32x4 v = ((const f32x4*)(x + (size_t)row*1024))[tid];
  float ss = v[0]*v[0]+v[1]*v[1]+v[2]*v[2]+v[3]*v[3];
  #pragma unroll
  for (int m=1;m<64;m<<=1) ss += __shfl_xor(ss, m);
  __shared__ float red[4];
  if (lane==0) red[wid] = ss;
  __syncthreads();
  float tot = red[0]+red[1]+red[2]+red[3];
  float inv = rsqrtf(tot*(1.f/1024.f) + 1e-6f);
  f32x4 gv = ((const f32x4*)g)[tid];
  #pragma unroll
  for (int i=0;i<4;i++){
    float val = v[i]*inv*gv[i];
    bf16 h,m; split2f(val,h,m);
    size_t idx = (size_t)row*1024 + tid*4 + i;
    o2[idx] = h; o2[H1PL + idx] = m;
  }
}

// ---------------- plain bf16 GEMM (MoE path), BK=64, XOR-swizzled, 128x128, single-buffer ----------------
// OUT: 1 = bf16, 2 = fused silu (g/u 16-interleaved B, ldc = N/2)
// Refuted variants (kept for the record): NT=2 (R13: occupancy cliff), explicit dbuf (R16: -10us).
template<int OUT, int GATHER, int GROUPED>
__global__ __launch_bounds__(256) void gemm_k(
    const bf16* __restrict__ Aptr, int lda,
    const bf16* __restrict__ Bt, long bMatStride,
    void* __restrict__ Cout, int ldc,
    const float* __restrict__ resid,
    const int* __restrict__ gidx,
    const int* __restrict__ grpBase,
    const int* __restrict__ grpCnt,
    int M, int K){
  int tid = threadIdx.x;
  int wid = tid >> 6, lane = tid & 63;
  int lr = lane & 15, lg = lane >> 4;
  int e = blockIdx.z;
  int base = GROUPED ? grpBase[e] : 0;
  int cnt  = GROUPED ? grpCnt[e]  : M;
  int m0, bn0;
  if (GROUPED){
    m0 = blockIdx.y * 128;
    bn0 = blockIdx.x * 128;
  } else {
    int gx = gridDim.x;
    int bid = blockIdx.y*gx + blockIdx.x;
    int cpx = (gx*gridDim.y)>>3;
    int swz = (bid&7)*cpx + (bid>>3);
    m0 = (swz/gx) * 128;
    bn0 = (swz%gx) * 128;
  }
  if (m0 >= cnt) return;
  const bf16* Bte = Bt + (size_t)e * bMatStride;

  __shared__ __align__(16) bf16 As[128*64];
  __shared__ __align__(16) bf16 Bs[128*64];

  int lrow = lane >> 3;                 // 0..7
  int cb   = (lane & 7) ^ lrow;         // pre-swizzled global col-block (16B units)
  int arow[4], brow[4];
  #pragma unroll
  for (int i=0;i<4;i++){
    int r = wid*8 + i*32 + lrow;
    int ar = m0 + r; if (ar > cnt-1) ar = cnt-1;
    arow[i] = GATHER ? gidx[base + ar] : (base + ar);
    brow[i] = bn0 + r;
  }

  f32x4 zero4 = {0.f,0.f,0.f,0.f};
  f32x4 acc[4][4];
  #pragma unroll
  for (int m=0;m<4;m++)
    #pragma unroll
    for (int n=0;n<4;n++) acc[m][n] = zero4;

  char* ldsA = (char*)As + wid*1024;
  char* ldsB = (char*)Bs + wid*1024;
  int wr = (wid>>1)*64, wc = (wid&1)*64;
  int sw = lr & 7;   // read-side XOR (row&7 == lr&7 since wr,m*16 are multiples of 8)

  for (int k0 = 0; k0 < K; k0 += 64){
    #pragma unroll
    for (int i=0;i<4;i++){
      gload_lds16(Aptr + (size_t)arow[i]*lda + k0 + cb*8, ldsA + i*4096);
      gload_lds16(Bte  + (size_t)brow[i]*K   + k0 + cb*8, ldsB + i*4096);
    }
    asm volatile("s_waitcnt vmcnt(0)" ::: "memory");
    __syncthreads();
    #pragma unroll
    for (int ks=0; ks<2; ks++){
      int pos = (ks*4 + lg) ^ sw;
      bf16x8 af[4], bfr[4];
      #pragma unroll
      for (int m=0;m<4;m++)
        af[m] = *(const bf16x8*)&As[(wr + m*16 + lr)*64 + pos*8];
      #pragma unroll
      for (int n=0;n<4;n++)
        bfr[n] = *(const bf16x8*)&Bs[(wc + n*16 + lr)*64 + pos*8];
      #pragma unroll
      for (int m=0;m<4;m++)
        #pragma unroll
        for (int n=0;n<4;n++)
          acc[m][n] = mfma16(af[m], bfr[n], acc[m][n]);
    }
    __syncthreads();
  }
  #pragma unroll
  for (int m=0;m<4;m++){
    #pragma unroll
    for (int j=0;j<4;j++){
      int gr = m0 + wr + m*16 + lg*4 + j;
      if (gr < cnt){
        size_t orow = (size_t)(base + gr);
        if (OUT==2){
          #pragma unroll
          for (int np=0;np<2;np++){
            float gv = acc[m][2*np][j], uv = acc[m][2*np+1][j];
            float ov = gv * uv / (1.f + __expf(-gv));
            int f = ((bn0+wc)>>1) + np*16 + lr;
            ((bf16*)Cout)[orow*ldc + f] = (bf16)ov;
          }
        } else {
          #pragma unroll
          for (int n=0;n<4;n++){
            int gc = bn0 + wc + n*16 + lr;
            ((bf16*)Cout)[orow*ldc + gc] = (bf16)acc[m][n][j];
          }
        }
      }
    }
  }
}

// ---------------- split-2 precise GEMM: 3 products (hh,hm,mh), C f32 (+resid) ----------------
template<int RESID>
__global__ __launch_bounds__(256) void gemm2_k(
    const bf16* __restrict__ A2, long aPL, int lda,
    const bf16* __restrict__ B2, long bPL, int K,
    float* __restrict__ C, int ldc,
    const float* __restrict__ resid){
  int tid = threadIdx.x;
  int wid = tid >> 6, lane = tid & 63;
  int lr = lane & 15, lg = lane >> 4;
  int gx = gridDim.x;
  int bid = blockIdx.y*gx + blockIdx.x;
  int cpx = (gx*gridDim.y)>>3;
  int swz = (bid&7)*cpx + (bid>>3);
  int m0 = (swz/gx) * 128;
  int bn0 = (swz%gx) * 128;

  __shared__ __align__(16) bf16 As[2*128*32];
  __shared__ __align__(16) bf16 Bs[2*128*32];

  int rA0 = tid >> 2, colA = (tid & 3) * 8;
  f32x4 zero4 = {0.f,0.f,0.f,0.f};
  f32x4 acc[4][4];
  #pragma unroll
  for (int m=0;m<4;m++)
    #pragma unroll
    for (int n=0;n<4;n++) acc[m][n] = zero4;

  int wr = (wid>>1)*64, wc = (wid&1)*64;

  for (int k0 = 0; k0 < K; k0 += 32){
    #pragma unroll
    for (int p=0;p<2;p++){
      #pragma unroll
      for (int i=0;i<2;i++){
        int r = rA0 + i*64;
        gload_lds16(A2 + (size_t)p*aPL + (size_t)(m0 + r)*lda + k0 + colA,
                    (char*)As + p*8192 + wid*1024 + i*4096);
        gload_lds16(B2 + (size_t)p*bPL + (size_t)(bn0 + r)*K + k0 + colA,
                    (char*)Bs + p*8192 + wid*1024 + i*4096);
      }
    }
    asm volatile("s_waitcnt vmcnt(0)" ::: "memory");
    __syncthreads();
    bf16x8 af[2][4], bfr[2][4];
    #pragma unroll
    for (int p=0;p<2;p++){
      #pragma unroll
      for (int m=0;m<4;m++) af[p][m]  = *(const bf16x8*)&As[p*4096 + (wr + m*16 + lr)*32 + lg*8];
      #pragma unroll
      for (int n=0;n<4;n++) bfr[p][n] = *(const bf16x8*)&Bs[p*4096 + (wc + n*16 + lr)*32 + lg*8];
    }
    #pragma unroll
    for (int m=0;m<4;m++)
      #pragma unroll
      for (int n=0;n<4;n++){
        f32x4 a = acc[m][n];
        a = mfma16(af[0][m], bfr[0][n], a);   // hh
        a = mfma16(af[0][m], bfr[1][n], a);   // hm
        a = mfma16(af[1][m], bfr[0][n], a);   // mh
        acc[m][n] = a;
      }
    __syncthreads();
  }
  #pragma unroll
  for (int m=0;m<4;m++){
    #pragma unroll
    for (int j=0;j<4;j++){
      size_t orow = (size_t)(m0 + wr + m*16 + lg*4 + j);
      #pragma unroll
      for (int n=0;n<4;n++){
        int gc = bn0 + wc + n*16 + lr;
        float v = acc[m][n][j];
        if (RESID) v += resid[orow*ldc + gc];
        C[orow*ldc + gc] = v;
      }
    }
  }
}

// ---------------- merged: per-head QK RMSNorm+RoPE (blocks < 20480) and V transpose (rest) ----------------
__global__ __launch_bounds__(256) void rv2_k(const float* __restrict__ qkv, bf16* __restrict__ Q2,
                                             bf16* __restrict__ K2, bf16* __restrict__ V2,
                                             const int* __restrict__ idxp,
                                             const float* __restrict__ qg, const float* __restrict__ kg){
  int bid = blockIdx.x;
  if (bid < 20480){
    int tid = threadIdx.x, wid = tid>>6, lane = tid&63;
    int u = bid*4 + wid;   // 0 .. TT*20-1
    int t = u / 20, r = u % 20;
    bool isq = (r < 16);
    int srcOff = isq ? r*64 : 1024 + (r-16)*64;
    float val = qkv[(size_t)t*1536 + srcOff + lane];
    float ss = val*val;
    #pragma unroll
    for (int m=1;m<64;m<<=1) ss += __shfl_xor(ss, m);
    float inv = rsqrtf(ss*(1.f/64.f) + 1e-6f);
    const float* gm = isq ? qg : kg;
    val = val * inv * gm[lane];
    bool rope = ((idxp[0] + 1) % 4) != 0;
    if (rope){
      int s = t & (TS-1);
      float fi = (float)(lane & ~1);
      float theta = (float)exp((double)fi * -0.14391156831212787);
      float ang = (float)s * theta;
      float sn, cs;
      sincosf(ang, &sn, &cs);
      float other = __shfl_xor(val, 1);
      val = (lane & 1) ? (other*sn + val*cs) : (val*cs - other*sn);
    }
    bf16 h,m2; split2f(val,h,m2);
    if (isq){
      size_t base = (size_t)t*1024 + r*64 + lane;
      Q2[base] = h; Q2[QPL + base] = m2;
    } else {
      size_t base = (size_t)t*256 + (r-16)*64 + lane;
      K2[base] = h; K2[KPL + base] = m2;
    }
  } else {
    int vb = bid - 20480;              // 0..1023
    int xb = vb & 1, yb = (vb>>1) & 63, z = vb >> 7;   // z = b*4+kvh
    __shared__ float tile[32][33];
    const float* s = qkv + (size_t)(z>>2)*((size_t)TS*1536) + (z&3)*64 + 1280;
    int r0 = yb*32, c0 = xb*32;
    int tx = threadIdx.x & 31, ty = threadIdx.x >> 5;
    #pragma unroll
    for (int i=0;i<4;i++)
      tile[ty+i*8][tx] = s[(size_t)(r0+ty+i*8)*1536 + c0+tx];
    __syncthreads();
    size_t zb = (size_t)z*(64*TS);
    #pragma unroll
    for (int i=0;i<4;i++){
      float v = tile[tx][ty+i*8];
      bf16 h,m; split2f(v,h,m);
      size_t o = zb + (size_t)(c0+ty+i*8)*TS + r0+tx;
      V2[o] = h; V2[VPL + o] = m;
    }
  }
}

// ---------------- precise chunked-causal GQA flash attention (2-limb, 3-product) ----------------
__global__ __launch_bounds__(256) void attn2_k(const bf16* __restrict__ Q2, const bf16* __restrict__ K2,
                                               const bf16* __restrict__ V2, bf16* __restrict__ A2,
                                               const int* __restrict__ idxp){
  int tid = threadIdx.x, wid = tid>>6, lane = tid&63;
  int lr = lane&15, lg = lane>>4;
  int flat = (blockIdx.z*gridDim.y + blockIdx.y)*gridDim.x + blockIdx.x;
  int swz = (flat&7)*128 + (flat>>3);
  int qt = swz & 31, h = (swz>>5)&15, b = swz>>9;
  int kvh = h >> 2;
  int q0 = qt*64;
  bool rope = ((idxp[0]+1) % 4) != 0;
  int kstart = rope ? (q0 / TCHUNK) * TCHUNK : 0;
  int ntiles = (q0 + 64 - kstart) >> 5;

  __shared__ __align__(16) bf16 Ks[2*32*64];   // swizzled
  __shared__ __align__(16) bf16 Vs[2*64*32];   // linear
  __shared__ __align__(16) bf16 Ps[4][2][16*32];

  bf16x8 qf[2][2];
  {
    size_t qrow = (size_t)(b*TS + q0 + wid*16 + lr);
    #pragma unroll
    for (int p=0;p<2;p++)
      #pragma unroll
      for (int kf=0;kf<2;kf++)
        qf[p][kf] = *(const bf16x8*)&Q2[(size_t)p*QPL + qrow*1024 + h*64 + kf*32 + lg*8];
  }

  int krow = tid>>3;
  int kcb  = (tid&7) ^ (krow&7);
  int vrow = tid>>2;
  int vcb  = tid&3;

  f32x4 o[4];
  f32x4 zero4 = {0.f,0.f,0.f,0.f};
  #pragma unroll
  for (int n=0;n<4;n++) o[n] = zero4;
  float mrow[4], lrow[4];
  #pragma unroll
  for (int j=0;j<4;j++){ mrow[j] = -1e30f; lrow[j] = 0.f; }

  for (int kt=0; kt<ntiles; kt++){
    int kt0 = kstart + kt*32;
    #pragma unroll
    for (int p=0;p<2;p++){
      gload_lds16(K2 + (size_t)p*KPL + ((size_t)(b*TS + kt0 + krow))*256 + kvh*64 + kcb*8,
                  (char*)Ks + p*4096 + wid*1024);
      gload_lds16(V2 + (size_t)p*VPL + ((size_t)((b*4 + kvh)*64 + vrow))*TS + kt0 + vcb*8,
                  (char*)Vs + p*4096 + wid*1024);
    }
    asm volatile("s_waitcnt vmcnt(0)" ::: "memory");
    __syncthreads();

    // QK^T: 3 limb-products (x2 k-frags = 6 MFMA per cf)
    f32x4 sc[2];
    #pragma unroll
    for (int cf=0; cf<2; cf++){
      int r = cf*16 + lr;
      int sw = (lr&7) << 3;
      bf16x8 kh0 = *(const bf16x8*)&Ks[0*2048 + r*64 + (((lg  )<<3) ^ sw)];
      bf16x8 kh1 = *(const bf16x8*)&Ks[0*2048 + r*64 + (((lg+4)<<3) ^ sw)];
      bf16x8 km0 = *(const bf16x8*)&Ks[1*2048 + r*64 + (((lg  )<<3) ^ sw)];
      bf16x8 km1 = *(const bf16x8*)&Ks[1*2048 + r*64 + (((lg+4)<<3) ^ sw)];
      f32x4 a = zero4;
      a = mfma16(qf[0][0], kh0, a); a = mfma16(qf[0][1], kh1, a);  // hh
      a = mfma16(qf[0][0], km0, a); a = mfma16(qf[0][1], km1, a);  // hm
      a = mfma16(qf[1][0], kh0, a); a = mfma16(qf[1][1], kh1, a);  // mh
      sc[cf] = a;
    }
    #pragma unroll
    for (int j=0;j<4;j++){
      int qtok = q0 + wid*16 + lg*4 + j;
      float pmax = -1e30f;
      #pragma unroll
      for (int cf=0;cf<2;cf++){
        int ktok = kt0 + cf*16 + lr;
        float sv = (ktok <= qtok) ? sc[cf][j]*0.125f : -1e30f;
        sc[cf][j] = sv;
        pmax = fmaxf(pmax, sv);
      }
      #pragma unroll
      for (int m=1;m<16;m<<=1) pmax = fmaxf(pmax, __shfl_xor(pmax, m));
      float mnew = fmaxf(mrow[j], pmax);
      float corr = __expf(mrow[j]-mnew);
      float psum = 0.f;
      #pragma unroll
      for (int cf=0;cf<2;cf++){
        float p = __expf(sc[cf][j]-mnew);
        sc[cf][j] = p;
        psum += p;
      }
      #pragma unroll
      for (int m=1;m<16;m<<=1) psum += __shfl_xor(psum, m);
      lrow[j] = lrow[j]*corr + psum;
      mrow[j] = mnew;
      #pragma unroll
      for (int n=0;n<4;n++) o[n][j] *= corr;
      #pragma unroll
      for (int cf=0;cf<2;cf++){
        float p = sc[cf][j];
        bf16 ph = (bf16)p;
        bf16 pl = (bf16)(p - (float)ph);
        int pidx = (lg*4+j)*32 + cf*16 + lr;
        Ps[wid][0][pidx] = ph;
        Ps[wid][1][pidx] = pl;
      }
    }
    __syncthreads();
    // PV: 3 limb-products (hh, hm, lh)
    bf16x8 pa0 = *(const bf16x8*)&Ps[wid][0][lr*32 + lg*8];
    bf16x8 pa1 = *(const bf16x8*)&Ps[wid][1][lr*32 + lg*8];
    #pragma unroll
    for (int n=0;n<4;n++){
      bf16x8 vh = *(const bf16x8*)&Vs[0*2048 + (n*16+lr)*32 + lg*8];
      bf16x8 vm = *(const bf16x8*)&Vs[1*2048 + (n*16+lr)*32 + lg*8];
      f32x4 a = o[n];
      a = mfma16(pa0, vh, a);   // hh
      a = mfma16(pa0, vm, a);   // hm
      a = mfma16(pa1, vh, a);   // lh
      o[n] = a;
    }
    __syncthreads();
  }
  #pragma unroll
  for (int j=0;j<4;j++){
    int qtok = q0 + wid*16 + lg*4 + j;
    float invl = 1.f / lrow[j];
    size_t rowb = ((size_t)(b*TS + qtok))*1024 + h*64;
    #pragma unroll
    for (int n=0;n<4;n++){
      float v = o[n][j]*invl;
      bf16 h2,m2; split2f(v,h2,m2);
      size_t oidx = rowb + n*16 + lr;
      A2[oidx] = h2; A2[APL + oidx] = m2;
    }
  }
}

// ---------------- fused f32 rmsnorm(h2) + router ----------------
__global__ __launch_bounds__(256) void rmsrouter_k(const float* __restrict__ x2, const float* __restrict__ g2,
                                                   const float* __restrict__ wr, bf16* __restrict__ h2,
                                                   int* __restrict__ topi, float* __restrict__ topw){
  int tid = threadIdx.x, wid = tid>>6, lane = tid&63;
  int t = blockIdx.x*4 + wid;
  const float* row = x2 + (size_t)t*1024;
  f32x4 xv[4];
  float ss = 0.f;
  #pragma unroll
  for (int j=0;j<4;j++){
    xv[j] = ((const f32x4*)row)[lane + j*64];
    ss += xv[j][0]*xv[j][0]+xv[j][1]*xv[j][1]+xv[j][2]*xv[j][2]+xv[j][3]*xv[j][3];
  }
  #pragma unroll
  for (int m=1;m<64;m<<=1) ss += __shfl_xor(ss, m);
  float inv = 1.f / sqrtf(ss*(1.f/1024.f) + 1e-6f);
  float a[8] = {0,0,0,0,0,0,0,0};
  #pragma unroll
  for (int j=0;j<4;j++){
    bf16x4 hb;
    #pragma unroll
    for (int c=0;c<4;c++){
      int d = (lane + j*64)*4 + c;
      float hv = xv[j][c]*inv*g2[d];
      hb[c] = (bf16)hv;
      f32x4 wa = ((const f32x4*)(wr + (size_t)d*8))[0];
      f32x4 wb = ((const f32x4*)(wr + (size_t)d*8))[1];
      a[0]+=hv*wa[0]; a[1]+=hv*wa[1]; a[2]+=hv*wa[2]; a[3]+=hv*wa[3];
      a[4]+=hv*wb[0]; a[5]+=hv*wb[1]; a[6]+=hv*wb[2]; a[7]+=hv*wb[3];
    }
    *(bf16x4*)(h2 + (size_t)t*1024 + (lane + j*64)*4) = hb;
  }
  #pragma unroll
  for (int e2=0;e2<8;e2++)
    #pragma unroll
    for (int m=1;m<64;m<<=1) a[e2] += __shfl_xor(a[e2], m);
  if (lane==0){
    int i0=0; float l0=a[0];
    #pragma unroll
    for (int e2=1;e2<8;e2++) if (a[e2] > l0){ l0=a[e2]; i0=e2; }
    int i1=-1; float l1=-1e30f;
    #pragma unroll
    for (int e2=0;e2<8;e2++){ if (e2==i0) continue; if (a[e2] > l1){ l1=a[e2]; i1=e2; } }
    float w0 = 1.f/(1.f + __expf(l1 - l0));
    topi[t*2]=i0; topi[t*2+1]=i1;
    topw[t*2]=w0; topw[t*2+1]=1.f-w0;
  }
}

// ---------------- single-block routing build (+ shared-expert group 8) ----------------
__global__ __launch_bounds__(1024) void route_build_k(const int* __restrict__ topi, int* __restrict__ rowsb,
                                                      int* __restrict__ t2p, int* __restrict__ cntp,
                                                      int* __restrict__ basep){
  __shared__ int wcnt[16][8], wbase[16][8], wcur[16][8];
  int tid = threadIdx.x, w = tid>>6;
  if (tid < 128){ wcnt[tid>>3][tid&7]=0; wcur[tid>>3][tid&7]=0; }
  __syncthreads();
  for (int i=tid; i<TT*2; i+=1024) atomicAdd(&wcnt[w][topi[i]], 1);
  __syncthreads();
  if (tid==0){
    int run=0;
    for (int e=0;e<8;e++){
      basep[e]=run; int s=run;
      for (int ww=0;ww<16;ww++){ wbase[ww][e]=run; run+=wcnt[ww][e]; }
      cntp[e]=run-s;
    }
    basep[8]=TT*2; cntp[8]=TT;   // shared expert: identity group
  }
  __syncthreads();
  for (int i=tid; i<TT*2; i+=1024){
    int e = topi[i];
    int p = wbase[w][e] + atomicAdd(&wcur[w][e], 1);
    rowsb[p] = i>>1;
    t2p[i] = p;
  }
  for (int i=tid; i<TT; i+=1024) rowsb[TT*2+i] = i;
}

// ---------------- final combine: out = x2 + sh + w0*e0 + w1*e1 ----------------
__global__ void combine_k(const float* __restrict__ x2, const bf16* __restrict__ eo,
                          const float* __restrict__ topw, const int* __restrict__ t2p,
                          float* __restrict__ out){
  int i = blockIdx.x*256 + threadIdx.x;
  int t = i >> 8, c = (i & 255)*4;
  int p0 = t2p[t*2], p1 = t2p[t*2+1];
  float w0 = topw[t*2], w1 = topw[t*2+1];
  f32x4 a = *(const f32x4*)&x2[(size_t)t*1024 + c];
  bf16x4 e0 = *(const bf16x4*)&eo[(size_t)p0*1024 + c];
  bf16x4 e1 = *(const bf16x4*)&eo[(size_t)p1*1024 + c];
  bf16x4 es = *(const bf16x4*)&eo[((size_t)(TT*2) + t)*1024 + c];
  f32x4 r;
  #pragma unroll
  for (int k=0;k<4;k++) r[k] = a[k] + (float)es[k] + w0*(float)e0[k] + w1*(float)e1[k];
  *(f32x4*)&out[(size_t)t*1024 + c] = r;
}

extern "C" void kernel_launch(void* const* d_in, const int* in_sizes, int n_in,
                              void* d_out, int out_size, void* d_ws, size_t ws_size,
                              hipStream_t stream){
  const float* x        = (const float*)d_in[0];
  const int*   idx      = (const int*)d_in[1];
  const float* gamma1   = (const float*)d_in[2];
  const float* gamma2   = (const float*)d_in[3];
  const float* qg       = (const float*)d_in[4];
  const float* kg       = (const float*)d_in[5];
  const float* w_q      = (const float*)d_in[6];
  const float* w_k      = (const float*)d_in[7];
  const float* w_v      = (const float*)d_in[8];
  const float* w_o      = (const float*)d_in[9];
  const float* w_router = (const float*)d_in[10];
  const float* sh_wg    = (const float*)d_in[11];
  const float* sh_wu    = (const float*)d_in[12];
  const float* sh_wd    = (const float*)d_in[13];
  const float* e_wg     = (const float*)d_in[14];
  const float* e_wu     = (const float*)d_in[15];
  const float* e_wd     = (const float*)d_in[16];
  float* out = (float*)d_out;

  char* ws = (char*)d_ws;
  size_t off = 0;
  auto alloc = [&](size_t n)->char*{ char* p = ws + off; off += (n + 255) & ~(size_t)255; return p; };

  const long PLQKV = (long)1536*1024;
  const long PLSQ  = (long)1024*1024;

  bf16* wqkv2  = (bf16*)alloc((size_t)2*1536*1024*2);
  bf16* wo2    = (bf16*)alloc((size_t)2*1024*1024*2);
  bf16* ewgu_t = (bf16*)alloc((size_t)9*2048*1024*2);   // 9th slot = shared expert
  bf16* ewd_t  = (bf16*)alloc((size_t)9*1024*1024*2);   // 9th slot = shared expert
  bf16* h1s    = (bf16*)alloc((size_t)2*TT*1024*2);
  float* qkvraw= (float*)alloc((size_t)TT*1536*4);
  bf16* q2     = (bf16*)alloc((size_t)2*TT*1024*2);
  bf16* k2     = (bf16*)alloc((size_t)2*TT*256*2);
  bf16* v2     = (bf16*)alloc((size_t)2*8*64*TS*2);
  float* x2    = (float*)alloc((size_t)TT*1024*4);
  bf16* gu     = (bf16*)alloc((size_t)(TT*3)*1024*2);   // 12288 rows
  bf16* eo     = (bf16*)alloc((size_t)(TT*3)*1024*2);   // 12288 rows
  int*   topi  = (int*)alloc((size_t)TT*2*4);
  float* topw  = (float*)alloc((size_t)TT*2*4);
  int*   rowsb = (int*)alloc((size_t)TT*3*4);
  int*   t2p   = (int*)alloc((size_t)TT*2*4);
  int*   cntp  = (int*)alloc(256);
  int*   basep = (int*)alloc(256);
  (void)ws_size; (void)in_sizes; (void)n_in; (void)out_size;

  bf16* shwgu_t = ewgu_t + (size_t)8*2048*1024;  // alias: 9th up slot
  bf16* shwd_t  = ewd_t  + (size_t)8*1024*1024;  // alias: 9th down slot
  bf16* a2      = (bf16*)qkvraw;     // attn output splits (qkvraw dead by then)
  bf16* h2      = q2;                // q2 dead after attention

  dim3 tb(32,8);
  // single merged weight-conversion launch (z: 0-3 precise 2-limb, 4-30 MoE)
  tcvt_all_k<<<dim3(32,32,31), tb, 0, stream>>>(w_q, w_k, w_v, w_o,
                                                sh_wg, sh_wu, sh_wd, e_wg, e_wu, e_wd,
                                                wqkv2, wo2, shwgu_t, shwd_t, ewgu_t, ewd_t);

  rmsnorm2_k<<<TT, 256, 0, stream>>>(x, gamma1, h1s);
  gemm2_k<0><<<dim3(12,32,1), 256, 0, stream>>>(h1s, (long)H1PL, 1024, wqkv2, PLQKV, 1024,
                                                qkvraw, 1536, nullptr);
  rv2_k<<<20480+1024, 256, 0, stream>>>(qkvraw, q2, k2, v2, idx, qg, kg);
  attn2_k<<<dim3(32,16,2), 256, 0, stream>>>(q2, k2, v2, a2, idx);
  gemm2_k<1><<<dim3(8,32,1), 256, 0, stream>>>(a2, (long)APL, 1024, wo2, PLSQ, 1024,
                                               x2, 1024, x);
  rmsrouter_k<<<TT/4, 256, 0, stream>>>(x2, gamma2, w_router, h2, topi, topw);
  route_build_k<<<1, 1024, 0, stream>>>(topi, rowsb, t2p, cntp, basep);
  // unified MoE (8 routed + shared as group 8): up+silu, then down  (BK=64 swizzled, 128x128)
  gemm_k<2,1,1><<<dim3(16,64,9), 256, 0, stream>>>(h2,1024, ewgu_t,(long)2048*1024, gu,1024,
                                                   nullptr, rowsb, basep, cntp, TT, 1024);
  gemm_k<1,0,1><<<dim3(8,64,9), 256, 0, stream>>>(gu,1024, ewd_t,(long)1024*1024, eo,1024,
                                                  nullptr, nullptr, basep, cntp, TT, 1024);
  combine_k<<<TT, 256, 0, stream>>>(x2, eo, topw, t2p, out);
}

// Round 18
// 383.587 us; speedup vs baseline: 1.0162x; 1.0038x over previous
//
#include <hip/hip_runtime.h>
#include <hip/hip_bf16.h>

#define TS    2048
#define TT    4096    // B*S
#define TCHUNK 512

typedef __bf16 bf16;
typedef __bf16 bf16x8 __attribute__((ext_vector_type(8)));
typedef __bf16 bf16x4 __attribute__((ext_vector_type(4)));
typedef float  f32x4  __attribute__((ext_vector_type(4)));

#define QPL ((size_t)TT*1024)
#define KPL ((size_t)TT*256)
#define VPL ((size_t)8*64*TS)
#define APL ((size_t)TT*1024)
#define H1PL ((size_t)TT*1024)

__device__ __forceinline__ f32x4 mfma16(bf16x8 a, bf16x8 b, f32x4 c){
  return __builtin_amdgcn_mfma_f32_16x16x32_bf16(a, b, c, 0, 0, 0);
}
__device__ __forceinline__ void gload_lds16(const void* g, void* lds){
  __builtin_amdgcn_global_load_lds(
      (const __attribute__((address_space(1))) unsigned int*)g,
      (__attribute__((address_space(3))) unsigned int*)lds, 16, 0, 0);
}
// 2-limb split; 3 cross products (hh,hm,mh) retain ~2^-18 relative accuracy.
__device__ __forceinline__ void split2f(float x, bf16& h, bf16& m){
  h = (bf16)x; m = (bf16)(x - (float)h);
}

// ---------------- merged weight conversion ----------------
// z=0..3: 2-limb split transpose (w_q, w_k, w_v, w_o)
// z=4..30: MoE 1-way bf16 transpose (g/u 16-row-interleaved)
__global__ __launch_bounds__(256) void tcvt_all_k(const float* __restrict__ wq, const float* __restrict__ wk,
                                                  const float* __restrict__ wv, const float* __restrict__ wo,
                                                  const float* __restrict__ shwg, const float* __restrict__ shwu,
                                                  const float* __restrict__ shwd, const float* __restrict__ ewg,
                                                  const float* __restrict__ ewu, const float* __restrict__ ewd,
                                                  bf16* __restrict__ wqkv2, bf16* __restrict__ wo2,
                                                  bf16* __restrict__ shwgu, bf16* __restrict__ shwd_t,
                                                  bf16* __restrict__ ewgu, bf16* __restrict__ ewd_t){
  int z = blockIdx.z;
  __shared__ float tile[32][33];
  int tx = threadIdx.x, ty = threadIdx.y;
  if (z < 4){
    const float* src; bf16* dst; int C; long pl, doff;
    if (z==0){ src=wq; dst=wqkv2; C=1024; pl=(long)1536*1024; doff=0; }
    else if (z==1){ src=wk; dst=wqkv2; C=256; pl=(long)1536*1024; doff=(long)1024*1024; }
    else if (z==2){ src=wv; dst=wqkv2; C=256; pl=(long)1536*1024; doff=(long)1280*1024; }
    else { src=wo; dst=wo2; C=1024; pl=(long)1024*1024; doff=0; }
    int c0 = blockIdx.x*32;
    if (c0 >= C) return;
    int r0 = blockIdx.y*32;
    #pragma unroll
    for (int i=0;i<4;i++)
      tile[ty+i*8][tx] = src[(size_t)(r0+ty+i*8)*C + c0+tx];
    __syncthreads();
    #pragma unroll
    for (int i=0;i<4;i++){
      float v = tile[tx][ty+i*8];
      bf16 h,m; split2f(v,h,m);
      size_t o = doff + (size_t)(c0+ty+i*8)*1024 + r0+tx;
      dst[o] = h; dst[pl + o] = m;
    }
  } else {
    int zz = z - 4;
    const float* src; bf16* dst; int mode;
    if (zz==0){ src=shwg; dst=shwgu; mode=0; }
    else if (zz==1){ src=shwu; dst=shwgu; mode=1; }
    else if (zz==2){ src=shwd; dst=shwd_t; mode=2; }
    else if (zz<11){ int e=zz-3;  src=ewg+(size_t)e*1048576; dst=ewgu+(size_t)e*2097152; mode=0; }
    else if (zz<19){ int e=zz-11; src=ewu+(size_t)e*1048576; dst=ewgu+(size_t)e*2097152; mode=1; }
    else           { int e=zz-19; src=ewd+(size_t)e*1048576; dst=ewd_t+(size_t)e*1048576; mode=2; }
    int r0 = blockIdx.y*32, c0 = blockIdx.x*32;
    #pragma unroll
    for (int i=0;i<4;i++)
      tile[ty+i*8][tx] = src[(size_t)(r0+ty+i*8)*1024 + c0+tx];
    __syncthreads();
    #pragma unroll
    for (int i=0;i<4;i++){
      int c = c0+ty+i*8;
      int orow = (mode==2) ? c : ((c>>4)*32 + (c&15) + (mode==1?16:0));
      dst[(size_t)orow*1024 + r0+tx] = (bf16)tile[tx][ty+i*8];
    }
  }
}

// ---------------- RMSNorm f32 -> 2-way split bf16 planes ----------------
__global__ __launch_bounds__(256) void rmsnorm2_k(const float* __restrict__ x, const float* __restrict__ g,
                                                  bf16* __restrict__ o2){
  int row = blockIdx.x, tid = threadIdx.x, wid = tid>>6, lane = tid&63;
  f32x4 v = ((const f32x4*)(x + (size_t)row*1024))[tid];
  float ss = v[0]*v[0]+v[1]*v[1]+v[2]*v[2]+v[3]*v[3];
  #pragma unroll
  for (int m=1;m<64;m<<=1) ss += __shfl_xor(ss, m);
  __shared__ float red[4];
  if (lane==0) red[wid] = ss;
  __syncthreads();
  float tot = red[0]+red[1]+red[2]+red[3];
  float inv = rsqrtf(tot*(1.f/1024.f) + 1e-6f);
  f32x4 gv = ((const f32x4*)g)[tid];
  #pragma unroll
  for (int i=0;i<4;i++){
    float val = v[i]*inv*gv[i];
    bf16 h,m; split2f(val,h,m);
    size_t idx = (size_t)row*1024 + tid*4 + i;
    o2[idx] = h; o2[H1PL + idx] = m;
  }
}

// ---------------- plain bf16 GEMM (MoE path), BK=64, XOR-swizzled, 128x128, single-buffer ----------------
// OUT: 1 = bf16, 2 = fused silu (g/u 16-interleaved B, ldc = N/2)
template<int OUT, int GATHER, int GROUPED>
__global__ __launch_bounds__(256) void gemm_k(
    const bf16* __restrict__ Aptr, int lda,
    const bf16* __restrict__ Bt, long bMatStride,
    void* __restrict__ Cout, int ldc,
    const float* __restrict__ resid,
    const int* __restrict__ gidx,
    const int* __restrict__ grpBase,
    const int* __restrict__ grpCnt,
    int M, int K){
  int tid = threadIdx.x;
  int wid = tid >> 6, lane = tid & 63;
  int lr = lane & 15, lg = lane >> 4;
  int e = blockIdx.z;
  int base = GROUPED ? grpBase[e] : 0;
  int cnt  = GROUPED ? grpCnt[e]  : M;
  int m0, bn0;
  if (GROUPED){
    m0 = blockIdx.y * 128;
    bn0 = blockIdx.x * 128;
  } else {
    int gx = gridDim.x;
    int bid = blockIdx.y*gx + blockIdx.x;
    int cpx = (gx*gridDim.y)>>3;
    int swz = (bid&7)*cpx + (bid>>3);
    m0 = (swz/gx) * 128;
    bn0 = (swz%gx) * 128;
  }
  if (m0 >= cnt) return;
  const bf16* Bte = Bt + (size_t)e * bMatStride;

  __shared__ __align__(16) bf16 As[128*64];
  __shared__ __align__(16) bf16 Bs[128*64];

  int lrow = lane >> 3;                 // 0..7
  int cb   = (lane & 7) ^ lrow;         // pre-swizzled global col-block (16B units)
  int arow[4], brow[4];
  #pragma unroll
  for (int i=0;i<4;i++){
    int r = wid*8 + i*32 + lrow;
    int ar = m0 + r; if (ar > cnt-1) ar = cnt-1;
    arow[i] = GATHER ? gidx[base + ar] : (base + ar);
    brow[i] = bn0 + r;
  }

  f32x4 zero4 = {0.f,0.f,0.f,0.f};
  f32x4 acc[4][4];
  #pragma unroll
  for (int m=0;m<4;m++)
    #pragma unroll
    for (int n=0;n<4;n++) acc[m][n] = zero4;

  char* ldsA = (char*)As + wid*1024;
  char* ldsB = (char*)Bs + wid*1024;
  int wr = (wid>>1)*64, wc = (wid&1)*64;
  int sw = lr & 7;   // read-side XOR (row&7 == lr&7 since wr,m*16 are multiples of 8)

  for (int k0 = 0; k0 < K; k0 += 64){
    #pragma unroll
    for (int i=0;i<4;i++){
      gload_lds16(Aptr + (size_t)arow[i]*lda + k0 + cb*8, ldsA + i*4096);
      gload_lds16(Bte  + (size_t)brow[i]*K   + k0 + cb*8, ldsB + i*4096);
    }
    asm volatile("s_waitcnt vmcnt(0)" ::: "memory");
    __syncthreads();
    #pragma unroll
    for (int ks=0; ks<2; ks++){
      int pos = (ks*4 + lg) ^ sw;
      bf16x8 af[4], bfr[4];
      #pragma unroll
      for (int m=0;m<4;m++)
        af[m] = *(const bf16x8*)&As[(wr + m*16 + lr)*64 + pos*8];
      #pragma unroll
      for (int n=0;n<4;n++)
        bfr[n] = *(const bf16x8*)&Bs[(wc + n*16 + lr)*64 + pos*8];
      #pragma unroll
      for (int m=0;m<4;m++)
        #pragma unroll
        for (int n=0;n<4;n++)
          acc[m][n] = mfma16(af[m], bfr[n], acc[m][n]);
    }
    __syncthreads();
  }
  #pragma unroll
  for (int m=0;m<4;m++){
    #pragma unroll
    for (int j=0;j<4;j++){
      int gr = m0 + wr + m*16 + lg*4 + j;
      if (gr < cnt){
        size_t orow = (size_t)(base + gr);
        if (OUT==2){
          #pragma unroll
          for (int np=0;np<2;np++){
            float gv = acc[m][2*np][j], uv = acc[m][2*np+1][j];
            float ov = gv * uv / (1.f + __expf(-gv));
            int f = ((bn0+wc)>>1) + np*16 + lr;
            ((bf16*)Cout)[orow*ldc + f] = (bf16)ov;
          }
        } else {
          #pragma unroll
          for (int n=0;n<4;n++){
            int gc = bn0 + wc + n*16 + lr;
            ((bf16*)Cout)[orow*ldc + gc] = (bf16)acc[m][n][j];
          }
        }
      }
    }
  }
}

// ---------------- split-2 precise GEMM: 3 products (hh,hm,mh), C f32 (+resid) ----------------
template<int RESID>
__global__ __launch_bounds__(256) void gemm2_k(
    const bf16* __restrict__ A2, long aPL, int lda,
    const bf16* __restrict__ B2, long bPL, int K,
    float* __restrict__ C, int ldc,
    const float* __restrict__ resid){
  int tid = threadIdx.x;
  int wid = tid >> 6, lane = tid & 63;
  int lr = lane & 15, lg = lane >> 4;
  int gx = gridDim.x;
  int bid = blockIdx.y*gx + blockIdx.x;
  int cpx = (gx*gridDim.y)>>3;
  int swz = (bid&7)*cpx + (bid>>3);
  int m0 = (swz/gx) * 128;
  int bn0 = (swz%gx) * 128;

  __shared__ __align__(16) bf16 As[2*128*32];
  __shared__ __align__(16) bf16 Bs[2*128*32];

  int rA0 = tid >> 2, colA = (tid & 3) * 8;
  f32x4 zero4 = {0.f,0.f,0.f,0.f};
  f32x4 acc[4][4];
  #pragma unroll
  for (int m=0;m<4;m++)
    #pragma unroll
    for (int n=0;n<4;n++) acc[m][n] = zero4;

  int wr = (wid>>1)*64, wc = (wid&1)*64;

  for (int k0 = 0; k0 < K; k0 += 32){
    #pragma unroll
    for (int p=0;p<2;p++){
      #pragma unroll
      for (int i=0;i<2;i++){
        int r = rA0 + i*64;
        gload_lds16(A2 + (size_t)p*aPL + (size_t)(m0 + r)*lda + k0 + colA,
                    (char*)As + p*8192 + wid*1024 + i*4096);
        gload_lds16(B2 + (size_t)p*bPL + (size_t)(bn0 + r)*K + k0 + colA,
                    (char*)Bs + p*8192 + wid*1024 + i*4096);
      }
    }
    asm volatile("s_waitcnt vmcnt(0)" ::: "memory");
    __syncthreads();
    bf16x8 af[2][4], bfr[2][4];
    #pragma unroll
    for (int p=0;p<2;p++){
      #pragma unroll
      for (int m=0;m<4;m++) af[p][m]  = *(const bf16x8*)&As[p*4096 + (wr + m*16 + lr)*32 + lg*8];
      #pragma unroll
      for (int n=0;n<4;n++) bfr[p][n] = *(const bf16x8*)&Bs[p*4096 + (wc + n*16 + lr)*32 + lg*8];
    }
    #pragma unroll
    for (int m=0;m<4;m++)
      #pragma unroll
      for (int n=0;n<4;n++){
        f32x4 a = acc[m][n];
        a = mfma16(af[0][m], bfr[0][n], a);   // hh
        a = mfma16(af[0][m], bfr[1][n], a);   // hm
        a = mfma16(af[1][m], bfr[0][n], a);   // mh
        acc[m][n] = a;
      }
    __syncthreads();
  }
  #pragma unroll
  for (int m=0;m<4;m++){
    #pragma unroll
    for (int j=0;j<4;j++){
      size_t orow = (size_t)(m0 + wr + m*16 + lg*4 + j);
      #pragma unroll
      for (int n=0;n<4;n++){
        int gc = bn0 + wc + n*16 + lr;
        float v = acc[m][n][j];
        if (RESID) v += resid[orow*ldc + gc];
        C[orow*ldc + gc] = v;
      }
    }
  }
}

// ---------------- merged: per-head QK RMSNorm+RoPE (blocks < 20480) and V transpose (rest) ----------------
__global__ __launch_bounds__(256) void rv2_k(const float* __restrict__ qkv, bf16* __restrict__ Q2,
                                             bf16* __restrict__ K2, bf16* __restrict__ V2,
                                             const int* __restrict__ idxp,
                                             const float* __restrict__ qg, const float* __restrict__ kg){
  int bid = blockIdx.x;
  if (bid < 20480){
    int tid = threadIdx.x, wid = tid>>6, lane = tid&63;
    int u = bid*4 + wid;   // 0 .. TT*20-1
    int t = u / 20, r = u % 20;
    bool isq = (r < 16);
    int srcOff = isq ? r*64 : 1024 + (r-16)*64;
    float val = qkv[(size_t)t*1536 + srcOff + lane];
    float ss = val*val;
    #pragma unroll
    for (int m=1;m<64;m<<=1) ss += __shfl_xor(ss, m);
    float inv = rsqrtf(ss*(1.f/64.f) + 1e-6f);
    const float* gm = isq ? qg : kg;
    val = val * inv * gm[lane];
    bool rope = ((idxp[0] + 1) % 4) != 0;
    if (rope){
      int s = t & (TS-1);
      float fi = (float)(lane & ~1);
      float theta = (float)exp((double)fi * -0.14391156831212787);
      float ang = (float)s * theta;
      float sn, cs;
      sincosf(ang, &sn, &cs);
      float other = __shfl_xor(val, 1);
      val = (lane & 1) ? (other*sn + val*cs) : (val*cs - other*sn);
    }
    bf16 h,m2; split2f(val,h,m2);
    if (isq){
      size_t base = (size_t)t*1024 + r*64 + lane;
      Q2[base] = h; Q2[QPL + base] = m2;
    } else {
      size_t base = (size_t)t*256 + (r-16)*64 + lane;
      K2[base] = h; K2[KPL + base] = m2;
    }
  } else {
    int vb = bid - 20480;              // 0..1023
    int xb = vb & 1, yb = (vb>>1) & 63, z = vb >> 7;   // z = b*4+kvh
    __shared__ float tile[32][33];
    const float* s = qkv + (size_t)(z>>2)*((size_t)TS*1536) + (z&3)*64 + 1280;
    int r0 = yb*32, c0 = xb*32;
    int tx = threadIdx.x & 31, ty = threadIdx.x >> 5;
    #pragma unroll
    for (int i=0;i<4;i++)
      tile[ty+i*8][tx] = s[(size_t)(r0+ty+i*8)*1536 + c0+tx];
    __syncthreads();
    size_t zb = (size_t)z*(64*TS);
    #pragma unroll
    for (int i=0;i<4;i++){
      float v = tile[tx][ty+i*8];
      bf16 h,m; split2f(v,h,m);
      size_t o = zb + (size_t)(c0+ty+i*8)*TS + r0+tx;
      V2[o] = h; V2[VPL + o] = m;
    }
  }
}

// ---------------- precise chunked-causal GQA flash attention (2-limb, 3-product) ----------------
__global__ __launch_bounds__(256) void attn2_k(const bf16* __restrict__ Q2, const bf16* __restrict__ K2,
                                               const bf16* __restrict__ V2, bf16* __restrict__ A2,
                                               const int* __restrict__ idxp){
  int tid = threadIdx.x, wid = tid>>6, lane = tid&63;
  int lr = lane&15, lg = lane>>4;
  int flat = (blockIdx.z*gridDim.y + blockIdx.y)*gridDim.x + blockIdx.x;
  int swz = (flat&7)*128 + (flat>>3);
  int qt = swz & 31, h = (swz>>5)&15, b = swz>>9;
  int kvh = h >> 2;
  int q0 = qt*64;
  bool rope = ((idxp[0]+1) % 4) != 0;
  int kstart = rope ? (q0 / TCHUNK) * TCHUNK : 0;
  int ntiles = (q0 + 64 - kstart) >> 5;

  __shared__ __align__(16) bf16 Ks[2*32*64];   // swizzled
  __shared__ __align__(16) bf16 Vs[2*64*32];   // linear
  __shared__ __align__(16) bf16 Ps[4][2][16*32];

  bf16x8 qf[2][2];
  {
    size_t qrow = (size_t)(b*TS + q0 + wid*16 + lr);
    #pragma unroll
    for (int p=0;p<2;p++)
      #pragma unroll
      for (int kf=0;kf<2;kf++)
        qf[p][kf] = *(const bf16x8*)&Q2[(size_t)p*QPL + qrow*1024 + h*64 + kf*32 + lg*8];
  }

  int krow = tid>>3;
  int kcb  = (tid&7) ^ (krow&7);
  int vrow = tid>>2;
  int vcb  = tid&3;

  f32x4 o[4];
  f32x4 zero4 = {0.f,0.f,0.f,0.f};
  #pragma unroll
  for (int n=0;n<4;n++) o[n] = zero4;
  float mrow[4], lrow[4];
  #pragma unroll
  for (int j=0;j<4;j++){ mrow[j] = -1e30f; lrow[j] = 0.f; }

  for (int kt=0; kt<ntiles; kt++){
    int kt0 = kstart + kt*32;
    #pragma unroll
    for (int p=0;p<2;p++){
      gload_lds16(K2 + (size_t)p*KPL + ((size_t)(b*TS + kt0 + krow))*256 + kvh*64 + kcb*8,
                  (char*)Ks + p*4096 + wid*1024);
      gload_lds16(V2 + (size_t)p*VPL + ((size_t)((b*4 + kvh)*64 + vrow))*TS + kt0 + vcb*8,
                  (char*)Vs + p*4096 + wid*1024);
    }
    asm volatile("s_waitcnt vmcnt(0)" ::: "memory");
    __syncthreads();

    // QK^T: 3 limb-products (x2 k-frags = 6 MFMA per cf)
    f32x4 sc[2];
    #pragma unroll
    for (int cf=0; cf<2; cf++){
      int r = cf*16 + lr;
      int sw = (lr&7) << 3;
      bf16x8 kh0 = *(const bf16x8*)&Ks[0*2048 + r*64 + (((lg  )<<3) ^ sw)];
      bf16x8 kh1 = *(const bf16x8*)&Ks[0*2048 + r*64 + (((lg+4)<<3) ^ sw)];
      bf16x8 km0 = *(const bf16x8*)&Ks[1*2048 + r*64 + (((lg  )<<3) ^ sw)];
      bf16x8 km1 = *(const bf16x8*)&Ks[1*2048 + r*64 + (((lg+4)<<3) ^ sw)];
      f32x4 a = zero4;
      a = mfma16(qf[0][0], kh0, a); a = mfma16(qf[0][1], kh1, a);  // hh
      a = mfma16(qf[0][0], km0, a); a = mfma16(qf[0][1], km1, a);  // hm
      a = mfma16(qf[1][0], kh0, a); a = mfma16(qf[1][1], kh1, a);  // mh
      sc[cf] = a;
    }
    #pragma unroll
    for (int j=0;j<4;j++){
      int qtok = q0 + wid*16 + lg*4 + j;
      float pmax = -1e30f;
      #pragma unroll
      for (int cf=0;cf<2;cf++){
        int ktok = kt0 + cf*16 + lr;
        float sv = (ktok <= qtok) ? sc[cf][j]*0.125f : -1e30f;
        sc[cf][j] = sv;
        pmax = fmaxf(pmax, sv);
      }
      #pragma unroll
      for (int m=1;m<16;m<<=1) pmax = fmaxf(pmax, __shfl_xor(pmax, m));
      float mnew = fmaxf(mrow[j], pmax);
      float corr = __expf(mrow[j]-mnew);
      float psum = 0.f;
      #pragma unroll
      for (int cf=0;cf<2;cf++){
        float p = __expf(sc[cf][j]-mnew);
        sc[cf][j] = p;
        psum += p;
      }
      #pragma unroll
      for (int m=1;m<16;m<<=1) psum += __shfl_xor(psum, m);
      lrow[j] = lrow[j]*corr + psum;
      mrow[j] = mnew;
      #pragma unroll
      for (int n=0;n<4;n++) o[n][j] *= corr;
      #pragma unroll
      for (int cf=0;cf<2;cf++){
        float p = sc[cf][j];
        bf16 ph = (bf16)p;
        bf16 pl = (bf16)(p - (float)ph);
        int pidx = (lg*4+j)*32 + cf*16 + lr;
        Ps[wid][0][pidx] = ph;
        Ps[wid][1][pidx] = pl;
      }
    }
    __syncthreads();
    // PV: 3 limb-products (hh, hm, lh)
    bf16x8 pa0 = *(const bf16x8*)&Ps[wid][0][lr*32 + lg*8];
    bf16x8 pa1 = *(const bf16x8*)&Ps[wid][1][lr*32 + lg*8];
    #pragma unroll
    for (int n=0;n<4;n++){
      bf16x8 vh = *(const bf16x8*)&Vs[0*2048 + (n*16+lr)*32 + lg*8];
      bf16x8 vm = *(const bf16x8*)&Vs[1*2048 + (n*16+lr)*32 + lg*8];
      f32x4 a = o[n];
      a = mfma16(pa0, vh, a);   // hh
      a = mfma16(pa0, vm, a);   // hm
      a = mfma16(pa1, vh, a);   // lh
      o[n] = a;
    }
    __syncthreads();
  }
  #pragma unroll
  for (int j=0;j<4;j++){
    int qtok = q0 + wid*16 + lg*4 + j;
    float invl = 1.f / lrow[j];
    size_t rowb = ((size_t)(b*TS + qtok))*1024 + h*64;
    #pragma unroll
    for (int n=0;n<4;n++){
      float v = o[n][j]*invl;
      bf16 h2,m2; split2f(v,h2,m2);
      size_t oidx = rowb + n*16 + lr;
      A2[oidx] = h2; A2[APL + oidx] = m2;
    }
  }
}

// ---------------- fused f32 rmsnorm(h2) + router ----------------
__global__ __launch_bounds__(256) void rmsrouter_k(const float* __restrict__ x2, const float* __restrict__ g2,
                                                   const float* __restrict__ wr, bf16* __restrict__ h2,
                                                   int* __restrict__ topi, float* __restrict__ topw){
  int tid = threadIdx.x, wid = tid>>6, lane = tid&63;
  int t = blockIdx.x*4 + wid;
  const float* row = x2 + (size_t)t*1024;
  f32x4 xv[4];
  float ss = 0.f;
  #pragma unroll
  for (int j=0;j<4;j++){
    xv[j] = ((const f32x4*)row)[lane + j*64];
    ss += xv[j][0]*xv[j][0]+xv[j][1]*xv[j][1]+xv[j][2]*xv[j][2]+xv[j][3]*xv[j][3];
  }
  #pragma unroll
  for (int m=1;m<64;m<<=1) ss += __shfl_xor(ss, m);
  float inv = 1.f / sqrtf(ss*(1.f/1024.f) + 1e-6f);
  float a[8] = {0,0,0,0,0,0,0,0};
  #pragma unroll
  for (int j=0;j<4;j++){
    bf16x4 hb;
    #pragma unroll
    for (int c=0;c<4;c++){
      int d = (lane + j*64)*4 + c;
      float hv = xv[j][c]*inv*g2[d];
      hb[c] = (bf16)hv;
      f32x4 wa = ((const f32x4*)(wr + (size_t)d*8))[0];
      f32x4 wb = ((const f32x4*)(wr + (size_t)d*8))[1];
      a[0]+=hv*wa[0]; a[1]+=hv*wa[1]; a[2]+=hv*wa[2]; a[3]+=hv*wa[3];
      a[4]+=hv*wb[0]; a[5]+=hv*wb[1]; a[6]+=hv*wb[2]; a[7]+=hv*wb[3];
    }
    *(bf16x4*)(h2 + (size_t)t*1024 + (lane + j*64)*4) = hb;
  }
  #pragma unroll
  for (int e2=0;e2<8;e2++)
    #pragma unroll
    for (int m=1;m<64;m<<=1) a[e2] += __shfl_xor(a[e2], m);
  if (lane==0){
    int i0=0; float l0=a[0];
    #pragma unroll
    for (int e2=1;e2<8;e2++) if (a[e2] > l0){ l0=a[e2]; i0=e2; }
    int i1=-1; float l1=-1e30f;
    #pragma unroll
    for (int e2=0;e2<8;e2++){ if (e2==i0) continue; if (a[e2] > l1){ l1=a[e2]; i1=e2; } }
    float w0 = 1.f/(1.f + __expf(l1 - l0));
    topi[t*2]=i0; topi[t*2+1]=i1;
    topw[t*2]=w0; topw[t*2+1]=1.f-w0;
  }
}

// ---------------- 3-phase multi-block routing build ----------------
// Phase A: per-block histogram of 256 topi entries (32 blocks)
__global__ __launch_bounds__(256) void route_hist_k(const int* __restrict__ topi, int* __restrict__ bhist){
  __shared__ int h[8];
  if (threadIdx.x < 8) h[threadIdx.x] = 0;
  __syncthreads();
  int i = blockIdx.x*256 + threadIdx.x;   // 32*256 = 8192 = TT*2
  atomicAdd(&h[topi[i]], 1);
  __syncthreads();
  if (threadIdx.x < 8) bhist[blockIdx.x*8 + threadIdx.x] = h[threadIdx.x];
}
// Phase B: scan 32x8 histogram -> per-block bases + expert bases/counts (+ shared group 8)
__global__ __launch_bounds__(256) void route_scan_k(const int* __restrict__ bhist, int* __restrict__ bbase,
                                                    int* __restrict__ cntp, int* __restrict__ basep){
  __shared__ int sh[256], sb[256];
  sh[threadIdx.x] = bhist[threadIdx.x];
  __syncthreads();
  if (threadIdx.x == 0){
    int run = 0;
    for (int e=0;e<8;e++){
      basep[e] = run; int s = run;
      for (int b=0;b<32;b++){ sb[b*8+e] = run; run += sh[b*8+e]; }
      cntp[e] = run - s;
    }
    basep[8] = TT*2; cntp[8] = TT;   // shared expert: identity group
  }
  __syncthreads();
  bbase[threadIdx.x] = sb[threadIdx.x];
}
// Phase C: scatter with within-block LDS ranks; blocks 0..15 also fill shared-expert identity rows
__global__ __launch_bounds__(256) void route_scatter_k(const int* __restrict__ topi, const int* __restrict__ bbase,
                                                       int* __restrict__ rowsb, int* __restrict__ t2p){
  __shared__ int lbase[8], lcur[8];
  if (threadIdx.x < 8){ lbase[threadIdx.x] = bbase[blockIdx.x*8 + threadIdx.x]; lcur[threadIdx.x] = 0; }
  __syncthreads();
  int i = blockIdx.x*256 + threadIdx.x;
  int e = topi[i];
  int p = lbase[e] + atomicAdd(&lcur[e], 1);
  rowsb[p] = i >> 1;
  t2p[i] = p;
  if (i < TT) rowsb[TT*2 + i] = i;
}

// ---------------- final combine: out = x2 + sh + w0*e0 + w1*e1 ----------------
__global__ void combine_k(const float* __restrict__ x2, const bf16* __restrict__ eo,
                          const float* __restrict__ topw, const int* __restrict__ t2p,
                          float* __restrict__ out){
  int i = blockIdx.x*256 + threadIdx.x;
  int t = i >> 8, c = (i & 255)*4;
  int p0 = t2p[t*2], p1 = t2p[t*2+1];
  float w0 = topw[t*2], w1 = topw[t*2+1];
  f32x4 a = *(const f32x4*)&x2[(size_t)t*1024 + c];
  bf16x4 e0 = *(const bf16x4*)&eo[(size_t)p0*1024 + c];
  bf16x4 e1 = *(const bf16x4*)&eo[(size_t)p1*1024 + c];
  bf16x4 es = *(const bf16x4*)&eo[((size_t)(TT*2) + t)*1024 + c];
  f32x4 r;
  #pragma unroll
  for (int k=0;k<4;k++) r[k] = a[k] + (float)es[k] + w0*(float)e0[k] + w1*(float)e1[k];
  *(f32x4*)&out[(size_t)t*1024 + c] = r;
}

extern "C" void kernel_launch(void* const* d_in, const int* in_sizes, int n_in,
                              void* d_out, int out_size, void* d_ws, size_t ws_size,
                              hipStream_t stream){
  const float* x        = (const float*)d_in[0];
  const int*   idx      = (const int*)d_in[1];
  const float* gamma1   = (const float*)d_in[2];
  const float* gamma2   = (const float*)d_in[3];
  const float* qg       = (const float*)d_in[4];
  const float* kg       = (const float*)d_in[5];
  const float* w_q      = (const float*)d_in[6];
  const float* w_k      = (const float*)d_in[7];
  const float* w_v      = (const float*)d_in[8];
  const float* w_o      = (const float*)d_in[9];
  const float* w_router = (const float*)d_in[10];
  const float* sh_wg    = (const float*)d_in[11];
  const float* sh_wu    = (const float*)d_in[12];
  const float* sh_wd    = (const float*)d_in[13];
  const float* e_wg     = (const float*)d_in[14];
  const float* e_wu     = (const float*)d_in[15];
  const float* e_wd     = (const float*)d_in[16];
  float* out = (float*)d_out;

  char* ws = (char*)d_ws;
  size_t off = 0;
  auto alloc = [&](size_t n)->char*{ char* p = ws + off; off += (n + 255) & ~(size_t)255; return p; };

  const long PLQKV = (long)1536*1024;
  const long PLSQ  = (long)1024*1024;

  bf16* wqkv2  = (bf16*)alloc((size_t)2*1536*1024*2);
  bf16* wo2    = (bf16*)alloc((size_t)2*1024*1024*2);
  bf16* ewgu_t = (bf16*)alloc((size_t)9*2048*1024*2);   // 9th slot = shared expert
  bf16* ewd_t  = (bf16*)alloc((size_t)9*1024*1024*2);   // 9th slot = shared expert
  bf16* h1s    = (bf16*)alloc((size_t)2*TT*1024*2);
  float* qkvraw= (float*)alloc((size_t)TT*1536*4);
  bf16* q2     = (bf16*)alloc((size_t)2*TT*1024*2);
  bf16* k2     = (bf16*)alloc((size_t)2*TT*256*2);
  bf16* v2     = (bf16*)alloc((size_t)2*8*64*TS*2);
  float* x2    = (float*)alloc((size_t)TT*1024*4);
  bf16* gu     = (bf16*)alloc((size_t)(TT*3)*1024*2);   // 12288 rows
  bf16* eo     = (bf16*)alloc((size_t)(TT*3)*1024*2);   // 12288 rows
  int*   topi  = (int*)alloc((size_t)TT*2*4);
  float* topw  = (float*)alloc((size_t)TT*2*4);
  int*   rowsb = (int*)alloc((size_t)TT*3*4);
  int*   t2p   = (int*)alloc((size_t)TT*2*4);
  int*   bhist = (int*)alloc(32*8*4);
  int*   bbase = (int*)alloc(32*8*4);
  int*   cntp  = (int*)alloc(256);
  int*   basep = (int*)alloc(256);
  (void)ws_size; (void)in_sizes; (void)n_in; (void)out_size;

  bf16* shwgu_t = ewgu_t + (size_t)8*2048*1024;  // alias: 9th up slot
  bf16* shwd_t  = ewd_t  + (size_t)8*1024*1024;  // alias: 9th down slot
  bf16* a2      = (bf16*)qkvraw;     // attn output splits (qkvraw dead by then)
  bf16* h2      = q2;                // q2 dead after attention

  dim3 tb(32,8);
  // single merged weight-conversion launch (z: 0-3 precise 2-limb, 4-30 MoE)
  tcvt_all_k<<<dim3(32,32,31), tb, 0, stream>>>(w_q, w_k, w_v, w_o,
                                                sh_wg, sh_wu, sh_wd, e_wg, e_wu, e_wd,
                                                wqkv2, wo2, shwgu_t, shwd_t, ewgu_t, ewd_t);

  rmsnorm2_k<<<TT, 256, 0, stream>>>(x, gamma1, h1s);
  gemm2_k<0><<<dim3(12,32,1), 256, 0, stream>>>(h1s, (long)H1PL, 1024, wqkv2, PLQKV, 1024,
                                                qkvraw, 1536, nullptr);
  rv2_k<<<20480+1024, 256, 0, stream>>>(qkvraw, q2, k2, v2, idx, qg, kg);
  attn2_k<<<dim3(32,16,2), 256, 0, stream>>>(q2, k2, v2, a2, idx);
  gemm2_k<1><<<dim3(8,32,1), 256, 0, stream>>>(a2, (long)APL, 1024, wo2, PLSQ, 1024,
                                               x2, 1024, x);
  rmsrouter_k<<<TT/4, 256, 0, stream>>>(x2, gamma2, w_router, h2, topi, topw);
  // 3-phase multi-block routing build (replaces 106us single-block route_build_k)
  route_hist_k<<<32, 256, 0, stream>>>(topi, bhist);
  route_scan_k<<<1, 256, 0, stream>>>(bhist, bbase, cntp, basep);
  route_scatter_k<<<32, 256, 0, stream>>>(topi, bbase, rowsb, t2p);
  // unified MoE (8 routed + shared as group 8): up+silu, then down  (BK=64 swizzled, 128x128)
  gemm_k<2,1,1><<<dim3(16,64,9), 256, 0, stream>>>(h2,1024, ewgu_t,(long)2048*1024, gu,1024,
                                                   nullptr, rowsb, basep, cntp, TT, 1024);
  gemm_k<1,0,1><<<dim3(8,64,9), 256, 0, stream>>>(gu,1024, ewd_t,(long)1024*1024, eo,1024,
                                                  nullptr, nullptr, basep, cntp, TT, 1024);
  combine_k<<<TT, 256, 0, stream>>>(x2, eo, topw, t2p, out);
}